// Round 11
// baseline (236.080 us; speedup 1.0000x reference)
//
#include <hip/hip_runtime.h>
#include <hip/hip_bf16.h>

#define BATCH 4
#define CIN   256
#define CMID  128
#define NPOS  4096
#define EPS   1e-5f
#define NQATT 4

typedef __bf16 bf16;
typedef __attribute__((ext_vector_type(8))) __bf16 bf16x8;
typedef __attribute__((ext_vector_type(4))) __bf16 bf16x4;
typedef __attribute__((ext_vector_type(4))) float  f32x4;

#define MFMA16(a, b, c) __builtin_amdgcn_mfma_f32_16x16x32_bf16((a), (b), (c), 0, 0, 0)

// XOR swizzle, 128B rows (8 chunks/row): chunk ^= row&7.
__device__ __forceinline__ int swz128(int row, int colb) {
    return row * 128 + ((((colb >> 4) ^ (row & 7)) << 4) | (colb & 15));
}
// 64B-row tiles ([rows][32 n] bf16): phys chunk = row*4 + (n4 ^ ((row>>1)&3)).
__device__ __forceinline__ int cswz(int row, int n4) {
    return (row * 4 + (n4 ^ ((row >> 1) & 3))) * 16;
}

// ---------------------------------------------------------------------------
// KT: x [B][CIN][N] f32  ->  xT [B][N][CIN] bf16   (LDS 64x64 tile transpose)
// ---------------------------------------------------------------------------
__global__ __launch_bounds__(256) void kt_transpose(const float* __restrict__ x,
                                                    bf16* __restrict__ xT) {
    __shared__ float tile[64][65];
    int n0 = blockIdx.x * 64, c0 = blockIdx.y * 64, b = blockIdx.z;
    const float* xp = x + (size_t)b * CIN * NPOS;
    int t = threadIdx.x;
    int lr = t >> 4;
    int lc4 = (t & 15) * 4;
    for (int p = 0; p < 4; ++p) {
        int c = lr + p * 16;
        f32x4 v = *reinterpret_cast<const f32x4*>(xp + (size_t)(c0 + c) * NPOS + n0 + lc4);
        tile[c][lc4 + 0] = v[0]; tile[c][lc4 + 1] = v[1];
        tile[c][lc4 + 2] = v[2]; tile[c][lc4 + 3] = v[3];
    }
    __syncthreads();
    bf16* xtp = xT + (size_t)b * NPOS * CIN;
    int cc = (t & 15) * 4;
    for (int p = 0; p < 4; ++p) {
        int n = (t >> 4) + p * 16;
        bf16x4 o;
        o[0] = (bf16)tile[cc + 0][n]; o[1] = (bf16)tile[cc + 1][n];
        o[2] = (bf16)tile[cc + 2][n]; o[3] = (bf16)tile[cc + 3][n];
        *reinterpret_cast<bf16x4*>(xtp + (size_t)(n0 + n) * CIN + c0 + cc) = o;
    }
}

// ---------------------------------------------------------------------------
// K1: q/k/v = W @ x + b.  grid (32 ntile, 3 which, B).  (r6-proven body.)
// ---------------------------------------------------------------------------
__global__ __launch_bounds__(256) void k_qkv(
    const float* __restrict__ Wq, const float* __restrict__ Wk, const float* __restrict__ Wv,
    const float* __restrict__ bq, const float* __restrict__ bk, const float* __restrict__ bv,
    const bf16* __restrict__ xT, bf16* __restrict__ qT, bf16* __restrict__ kT,
    bf16* __restrict__ vC) {
    __shared__ __align__(16) char a_lds[128 * 128];
    __shared__ __align__(16) char b_lds[128 * 128];
    int n0 = blockIdx.x * 128, which = blockIdx.y, b = blockIdx.z;
    const float* W    = which == 0 ? Wq : (which == 1 ? Wk : Wv);
    const float* bias = which == 0 ? bq : (which == 1 ? bk : bv);
    int t = threadIdx.x, lane = t & 63, w = t >> 6, wy = w >> 1, wx = w & 1;
    const bf16* xb = xT + (size_t)b * NPOS * CIN;

    f32x4 acc[4][4] = {};
    for (int k0 = 0; k0 < 256; k0 += 64) {
        __syncthreads();
        for (int i = 0; i < 8; ++i) {
            int idx = t + i * 256;
            int row = idx >> 4, c4 = (idx & 15) * 4;
            f32x4 v = *reinterpret_cast<const f32x4*>(W + (size_t)row * CIN + k0 + c4);
            bf16x4 o; o[0] = (bf16)v[0]; o[1] = (bf16)v[1]; o[2] = (bf16)v[2]; o[3] = (bf16)v[3];
            *reinterpret_cast<bf16x4*>(a_lds + swz128(row, c4 * 2)) = o;
        }
        for (int i = 0; i < 4; ++i) {
            int idx = t + i * 256;
            int row = idx >> 3, cb = (idx & 7) * 16;
            bf16x8 vv = *reinterpret_cast<const bf16x8*>(xb + (size_t)(n0 + row) * CIN + k0 + cb / 2);
            *reinterpret_cast<bf16x8*>(b_lds + swz128(row, cb)) = vv;
        }
        __syncthreads();
        for (int ks = 0; ks < 2; ++ks) {
            int kb = ks * 64 + (lane >> 4) * 16;
            bf16x8 af[4], bfr[4];
            for (int i = 0; i < 4; ++i)
                af[i] = *reinterpret_cast<const bf16x8*>(a_lds + swz128(wy * 64 + i * 16 + (lane & 15), kb));
            for (int j = 0; j < 4; ++j)
                bfr[j] = *reinterpret_cast<const bf16x8*>(b_lds + swz128(wx * 64 + j * 16 + (lane & 15), kb));
            for (int i = 0; i < 4; ++i)
                for (int j = 0; j < 4; ++j)
                    acc[i][j] = MFMA16(af[i], bfr[j], acc[i][j]);
        }
    }
    int rg = lane >> 4, cl = lane & 15;
    for (int i = 0; i < 4; ++i) {
        int ch0 = wy * 64 + i * 16 + rg * 4;
        f32x4 bv4 = *reinterpret_cast<const f32x4*>(bias + ch0);
        for (int j = 0; j < 4; ++j) {
            int n = n0 + wx * 64 + j * 16 + cl;
            f32x4 d = acc[i][j];
            for (int r = 0; r < 4; ++r) d[r] += bv4[r];
            if (which == 2) {
                for (int r = 0; r < 4; ++r)
                    vC[((size_t)b * CMID + ch0 + r) * NPOS + n] = (bf16)d[r];
            } else {
                bf16x4 o; o[0] = (bf16)d[0]; o[1] = (bf16)d[1]; o[2] = (bf16)d[2]; o[3] = (bf16)d[3];
                bf16* dst = (which == 0 ? qT : kT);
                *reinterpret_cast<bf16x4*>(dst + ((size_t)b * NPOS + n) * CMID + ch0) = o;
            }
        }
    }
}

// ---------------------------------------------------------------------------
// K2: zpart[mq][b][n] = sum_{m in eighth mq} exp(S[n,m]).
// NO LDS, NO barriers: k-frags persistent in regs; q fragments read directly
// from global (per-combo q-stream 128KB, L2-resident via XCD decode; all 4
// waves read the same 16KB q-tile -> L1 hits).  Flat grid 1024, mq = xcd.
// ---------------------------------------------------------------------------
__global__ __launch_bounds__(256) void k_zrow(const bf16* __restrict__ qT,
                                              const bf16* __restrict__ kT,
                                              float* __restrict__ zpart) {
    int l = blockIdx.x;
    int xcd = l & 7, slot = l >> 3;
    int mq = xcd, b = slot & 3;                      // combo (mq,b): 4 per XCD
    int n0 = (slot >> 2) * 128;
    int t = threadIdx.x, lane = t & 63, w = t >> 6;
    int cl = lane & 15, g = lane >> 4;
    const bf16* qb = qT + (size_t)b * NPOS * CMID;
    const bf16* kb = kT + (size_t)b * NPOS * CMID;

    bf16x8 kreg[2][4];                               // wave's n-cols, in regs
    for (int jn = 0; jn < 2; ++jn)
        for (int ks = 0; ks < 4; ++ks)
            kreg[jn][ks] = *reinterpret_cast<const bf16x8*>(
                kb + (size_t)(n0 + w * 32 + jn * 16 + cl) * CMID + ks * 32 + g * 8);

    int mbeg = mq * (NPOS / 8);
    float zacc[2] = {0.f, 0.f};
    for (int m0 = mbeg; m0 < mbeg + NPOS / 8; m0 += 64) {
        f32x4 acc[4][2] = {};
        __builtin_amdgcn_s_setprio(1);
        for (int ks = 0; ks < 4; ++ks) {
            bf16x8 qf[4];
            for (int im = 0; im < 4; ++im)
                qf[im] = *reinterpret_cast<const bf16x8*>(
                    qb + (size_t)(m0 + im * 16 + cl) * CMID + ks * 32 + g * 8);
            for (int im = 0; im < 4; ++im)
                for (int jn = 0; jn < 2; ++jn)
                    acc[im][jn] = MFMA16(qf[im], kreg[jn][ks], acc[im][jn]);
        }
        __builtin_amdgcn_s_setprio(0);
        for (int im = 0; im < 4; ++im)
            for (int jn = 0; jn < 2; ++jn)
                for (int r = 0; r < 4; ++r)
                    zacc[jn] += __expf(acc[im][jn][r]);
    }
    for (int jn = 0; jn < 2; ++jn) {
        zacc[jn] += __shfl_xor(zacc[jn], 16);
        zacc[jn] += __shfl_xor(zacc[jn], 32);
    }
    if (g == 0) {
        float* zp = zpart + ((size_t)mq * BATCH + b) * NPOS;
        zp[n0 + w * 32 + cl]      = zacc[0];
        zp[n0 + w * 32 + 16 + cl] = zacc[1];
    }
}

// ---------------------------------------------------------------------------
// K3: invZ = 1 / sum_{s<8} zpart[s].
// ---------------------------------------------------------------------------
__global__ __launch_bounds__(256) void k_rcp(const float* __restrict__ zpart,
                                             float* __restrict__ invZ) {
    int i = (blockIdx.x * 256 + threadIdx.x) * 4;
    f32x4 s = {0.f, 0.f, 0.f, 0.f};
    for (int p = 0; p < 8; ++p) {
        f32x4 a = *reinterpret_cast<const f32x4*>(zpart + (size_t)p * BATCH * NPOS + i);
        for (int r = 0; r < 4; ++r) s[r] += a[r];
    }
    f32x4 o;
    for (int r = 0; r < 4; ++r) o[r] = 1.f / s[r];
    *reinterpret_cast<f32x4*>(invZ + i) = o;
}

// ---------------------------------------------------------------------------
// K3b: vC[c,n] *= invZ[n]  (in-place).
// ---------------------------------------------------------------------------
__global__ __launch_bounds__(256) void k_vscale(bf16* __restrict__ vC,
                                                const float* __restrict__ invZ) {
    int idx = blockIdx.x * 256 + threadIdx.x;
    int b = idx >> 16;
    int n8 = idx & (NPOS / 8 - 1);
    bf16x8 v = *reinterpret_cast<const bf16x8*>(vC + (size_t)idx * 8);
    const float* iz = invZ + (size_t)b * NPOS + n8 * 8;
    f32x4 i0 = *reinterpret_cast<const f32x4*>(iz);
    f32x4 i1 = *reinterpret_cast<const f32x4*>(iz + 4);
    bf16x8 o;
    for (int r = 0; r < 4; ++r) {
        o[r]     = (bf16)((float)v[r]     * i0[r]);
        o[r + 4] = (bf16)((float)v[r + 4] * i1[r]);
    }
    *reinterpret_cast<bf16x8*>(vC + (size_t)idx * 8) = o;
}

// ---------------------------------------------------------------------------
// K4: y[m][c] = sum_n exp(S[n,m]) vs[c,n]  (vs = invZ-prescaled v).
// NO k/v LDS staging, NO barriers: k/v fragments read directly from global.
// Per-combo k/v = 512KB; XCD decode (r9-proven, FETCH 12MB) keeps them
// L2-resident; 4 waves/block read the same 32KB tile -> L1 hits.  Only LDS
// is wave-private P (8KB).  Waves free-run with natural phase stagger.
// Flat grid 512.  No launch_bounds min-waves (r8/r10 lesson: forcing 4/EU
// caps arch-VGPRs at 64 -> scratch spill catastrophe).
// ---------------------------------------------------------------------------
__global__ __launch_bounds__(256) void k_attn(const bf16* __restrict__ qT,
                                              const bf16* __restrict__ kT,
                                              const bf16* __restrict__ vS,
                                              bf16* __restrict__ ys) {
    __shared__ __align__(16) char p_lds[128 * 64];   // [128 m][32 n] cswz, 8KB
    int l = blockIdx.x;
    int xcd = l & 7, slot = l >> 3;
    int combo = xcd * 2 + (slot & 1);                // 16 combos (nq,b), 2/XCD
    int m0 = (slot >> 1) * 128;
    int nq = combo >> 2, b = combo & 3;
    int t = threadIdx.x, lane = t & 63, w = t >> 6;
    int cl = lane & 15, g = lane >> 4;
    const bf16* qb = qT + (size_t)b * NPOS * CMID;
    const bf16* kb = kT + (size_t)b * NPOS * CMID;
    const bf16* vb = vS + (size_t)b * CMID * NPOS;

    // q fragments (B-operand): wave owns m-cols m0 + w*32 + jm*16 + cl
    bf16x8 qreg[2][4];
    for (int jm = 0; jm < 2; ++jm)
        for (int ks = 0; ks < 4; ++ks)
            qreg[jm][ks] = *reinterpret_cast<const bf16x8*>(
                qb + (size_t)(m0 + w * 32 + jm * 16 + cl) * CMID + ks * 32 + g * 8);

    f32x4 acc2[2][8] = {};                           // y[m: wave's 32][c: 128]
    int nbeg = nq * (NPOS / NQATT);
    for (int s = 0; s < NPOS / NQATT / 64; ++s) {
        int n0 = nbeg + s * 64;
        // S^T: acc1[in][jm] = D[n = in*16+g*4+r][m = w*32+jm*16+cl]
        // k fragments direct from global (L1/L2).
        f32x4 acc1[4][2] = {};
        __builtin_amdgcn_s_setprio(1);
        for (int ks = 0; ks < 4; ++ks) {
            bf16x8 kf[4];
            for (int in = 0; in < 4; ++in)
                kf[in] = *reinterpret_cast<const bf16x8*>(
                    kb + (size_t)(n0 + in * 16 + cl) * CMID + ks * 32 + g * 8);
            for (int in = 0; in < 4; ++in)
                for (int jm = 0; jm < 2; ++jm)
                    acc1[in][jm] = MFMA16(kf[in], qreg[jm][ks], acc1[in][jm]);
        }
        __builtin_amdgcn_s_setprio(0);
        // Two n-halves: write wave-private P half (K=32), then PV it with v
        // fragments direct from global.
        #pragma unroll
        for (int ih = 0; ih < 2; ++ih) {
            #pragma unroll
            for (int in2 = 0; in2 < 2; ++in2)
                #pragma unroll
                for (int jm = 0; jm < 2; ++jm) {
                    int m = w * 32 + jm * 16 + cl;
                    bf16x4 o;
                    for (int r = 0; r < 4; ++r)
                        o[r] = (bf16)__expf(acc1[ih * 2 + in2][jm][r]);
                    *reinterpret_cast<bf16x4*>(p_lds + cswz(m, in2 * 2 + (g >> 1)) + (g & 1) * 8) = o;
                }
            bf16x8 af[2];
            for (int jm = 0; jm < 2; ++jm)
                af[jm] = *reinterpret_cast<const bf16x8*>(p_lds + cswz(w * 32 + jm * 16 + cl, g));
            __builtin_amdgcn_s_setprio(1);
            for (int j = 0; j < 8; ++j) {
                bf16x8 vf = *reinterpret_cast<const bf16x8*>(
                    vb + (size_t)(j * 16 + cl) * NPOS + n0 + ih * 32 + g * 8);
                for (int jm = 0; jm < 2; ++jm)
                    acc2[jm][j] = MFMA16(af[jm], vf, acc2[jm][j]);
            }
            __builtin_amdgcn_s_setprio(0);
        }
    }
    bf16* yb = ys + (size_t)nq * BATCH * NPOS * CMID
             + ((size_t)b * NPOS + m0) * CMID;
    for (int jm = 0; jm < 2; ++jm)
        for (int j = 0; j < 8; ++j) {
            int c = j * 16 + cl;
            for (int r = 0; r < 4; ++r) {
                int m = w * 32 + jm * 16 + g * 4 + r;
                yb[(size_t)m * CMID + c] = (bf16)acc2[jm][j][r];
            }
        }
}

// ---------------------------------------------------------------------------
// K5: out = (Ww @ sum_{s<ns} y_s + bw)*inv + add + x. grid (64 mtile,2 ot,B).
// ---------------------------------------------------------------------------
__global__ __launch_bounds__(256) void k_out(
    const float* __restrict__ Ww, const float* __restrict__ bw,
    const float* __restrict__ gamma, const float* __restrict__ beta,
    const float* __restrict__ mean, const float* __restrict__ var,
    const bf16* __restrict__ ys, int ns,
    const float* __restrict__ x, float* __restrict__ out) {
    __shared__ __align__(16) char a_lds[128 * 128];  // [128 o][64 c] swz
    __shared__ __align__(16) char b_lds[64 * 128];   // [64 m][64 c] swz
    int m0 = blockIdx.x * 64, o0 = blockIdx.y * 128, b = blockIdx.z;
    int t = threadIdx.x, lane = t & 63, w = t >> 6, wy = w >> 1, wx = w & 1;
    const size_t SL = (size_t)BATCH * NPOS * CMID;   // slice stride (elems)
    f32x4 acc[4][2] = {};
    for (int k0 = 0; k0 < 128; k0 += 64) {
        __syncthreads();
        for (int i = 0; i < 8; ++i) {
            int idx = t + i * 256, row = idx >> 4, c4 = (idx & 15) * 4;
            f32x4 v = *reinterpret_cast<const f32x4*>(Ww + (size_t)(o0 + row) * CMID + k0 + c4);
            bf16x4 o; o[0] = (bf16)v[0]; o[1] = (bf16)v[1]; o[2] = (bf16)v[2]; o[3] = (bf16)v[3];
            *reinterpret_cast<bf16x4*>(a_lds + swz128(row, c4 * 2)) = o;
        }
        for (int i = 0; i < 4; ++i) {
            int idx = t + i * 256, row = idx >> 4, c4 = (idx & 15) * 4;
            size_t yoff = ((size_t)b * NPOS + m0 + row) * CMID + k0 + c4;
            float sacc[4] = {0.f, 0.f, 0.f, 0.f};
            for (int p = 0; p < ns; ++p) {
                bf16x4 a = *reinterpret_cast<const bf16x4*>(ys + (size_t)p * SL + yoff);
                for (int r = 0; r < 4; ++r) sacc[r] += (float)a[r];
            }
            bf16x4 o;
            for (int r = 0; r < 4; ++r) o[r] = (bf16)sacc[r];
            *reinterpret_cast<bf16x4*>(b_lds + swz128(row, c4 * 2)) = o;
        }
        __syncthreads();
        for (int ks = 0; ks < 2; ++ks) {
            int kb = ks * 64 + (lane >> 4) * 16;
            bf16x8 af[4], bfr[2];
            for (int i = 0; i < 4; ++i)
                af[i] = *reinterpret_cast<const bf16x8*>(a_lds + swz128(wy * 64 + i * 16 + (lane & 15), kb));
            for (int j = 0; j < 2; ++j)
                bfr[j] = *reinterpret_cast<const bf16x8*>(b_lds + swz128(wx * 32 + j * 16 + (lane & 15), kb));
            for (int i = 0; i < 4; ++i)
                for (int j = 0; j < 2; ++j)
                    acc[i][j] = MFMA16(af[i], bfr[j], acc[i][j]);
        }
    }
    int rg = lane >> 4, cl = lane & 15;
    const float* xb = x + (size_t)b * CIN * NPOS;
    float* ob = out + (size_t)b * CIN * NPOS;
    for (int i = 0; i < 4; ++i) {
        int och0 = o0 + wy * 64 + i * 16 + rg * 4;
        f32x4 gg = *reinterpret_cast<const f32x4*>(gamma + och0);
        f32x4 be = *reinterpret_cast<const f32x4*>(beta + och0);
        f32x4 mu = *reinterpret_cast<const f32x4*>(mean + och0);
        f32x4 va = *reinterpret_cast<const f32x4*>(var + och0);
        f32x4 bb = *reinterpret_cast<const f32x4*>(bw + och0);
        float invv[4], addv[4];
        for (int r = 0; r < 4; ++r) {
            invv[r] = gg[r] / sqrtf(va[r] + EPS);
            addv[r] = be[r] - mu[r] * invv[r];
        }
        for (int j = 0; j < 2; ++j) {
            int m = m0 + wx * 32 + j * 16 + cl;
            for (int r = 0; r < 4; ++r) {
                float z = (acc[i][j][r] + bb[r]) * invv[r] + addv[r];
                ob[(size_t)(och0 + r) * NPOS + m] = z + xb[(size_t)(och0 + r) * NPOS + m];
            }
        }
    }
}

// ---------------------------------------------------------------------------
extern "C" void kernel_launch(void* const* d_in, const int* in_sizes, int n_in,
                              void* d_out, int out_size, void* d_ws, size_t ws_size,
                              hipStream_t stream) {
    const float* x     = (const float*)d_in[0];
    const float* Wq    = (const float*)d_in[1];
    const float* bq    = (const float*)d_in[2];
    const float* Wk    = (const float*)d_in[3];
    const float* bk    = (const float*)d_in[4];
    const float* Wv    = (const float*)d_in[5];
    const float* bv    = (const float*)d_in[6];
    const float* Ww    = (const float*)d_in[7];
    const float* bw    = (const float*)d_in[8];
    const float* gamma = (const float*)d_in[9];
    const float* beta  = (const float*)d_in[10];
    const float* mean  = (const float*)d_in[11];
    const float* var   = (const float*)d_in[12];
    float* out = (float*)d_out;

    const size_t slice = (size_t)BATCH * NPOS * CMID * 2;   // 4 MB

    char* p = (char*)d_ws;
    bf16* ys = (bf16*)p;        p += (size_t)NQATT * slice; // 16 MB (4 slices)
    bf16* qT = (bf16*)p;        p += slice;                 // 4 MB
    bf16* kT = (bf16*)p;        p += slice;                 // 4 MB
    bf16* vC = (bf16*)p;        p += slice;                 // 4 MB
    float* zpart = (float*)p;   p += (size_t)8 * BATCH * NPOS * 4;  // 512 KB
    float* invZ = (float*)p;                                        // 64 KB
    bf16* xT = (bf16*)d_ws;     // overlays ys[0..3]; dead before k_attn writes

    kt_transpose<<<dim3(NPOS / 64, CIN / 64, BATCH), 256, 0, stream>>>(x, xT);
    k_qkv<<<dim3(NPOS / 128, 3, BATCH), 256, 0, stream>>>(Wq, Wk, Wv, bq, bk, bv, xT, qT, kT, vC);
    k_zrow<<<dim3(1024), 256, 0, stream>>>(qT, kT, zpart);
    k_rcp<<<dim3(BATCH * NPOS / 1024), 256, 0, stream>>>(zpart, invZ);
    k_vscale<<<dim3(BATCH * CMID * NPOS / 8 / 256), 256, 0, stream>>>(vC, invZ);
    k_attn<<<dim3(512), 256, 0, stream>>>(qT, kT, vC, ys);
    k_out<<<dim3(NPOS / 64, 2, BATCH), 256, 0, stream>>>(Ww, bw, gamma, beta, mean, var, ys, NQATT, x, out);
}

// Round 12
// 110.132 us; speedup vs baseline: 2.1436x; 2.1436x over previous
//
#include <hip/hip_runtime.h>
#include <hip/hip_bf16.h>

#define BATCH 4
#define CIN   256
#define CMID  128
#define NPOS  4096
#define EPS   1e-5f
#define NQATT 4

typedef __bf16 bf16;
typedef __attribute__((ext_vector_type(8))) __bf16 bf16x8;
typedef __attribute__((ext_vector_type(4))) __bf16 bf16x4;
typedef __attribute__((ext_vector_type(4))) float  f32x4;

#define MFMA16(a, b, c) __builtin_amdgcn_mfma_f32_16x16x32_bf16((a), (b), (c), 0, 0, 0)

// async global->LDS DMA, 16B per lane, dest = wave-uniform base + lane*16
#define GLDS(gsrc, ldst) \
    __builtin_amdgcn_global_load_lds( \
        (const __attribute__((address_space(1))) void*)(gsrc), \
        (__attribute__((address_space(3))) void*)(ldst), 16, 0, 0)

// XOR swizzle, 256B rows (16 chunks/row): chunk ^= row&7.
__device__ __forceinline__ int swz256(int row, int colb) {
    return row * 256 + ((((colb >> 4) ^ (row & 7)) << 4) | (colb & 15));
}
// XOR swizzle, 128B rows (8 chunks/row): chunk ^= row&7.
__device__ __forceinline__ int swz128(int row, int colb) {
    return row * 128 + ((((colb >> 4) ^ (row & 7)) << 4) | (colb & 15));
}

// ---------------------------------------------------------------------------
// KT: x [B][CIN][N] f32  ->  xT [B][N][CIN] bf16   (LDS 64x64 tile transpose)
// ---------------------------------------------------------------------------
__global__ __launch_bounds__(256) void kt_transpose(const float* __restrict__ x,
                                                    bf16* __restrict__ xT) {
    __shared__ float tile[64][65];
    int n0 = blockIdx.x * 64, c0 = blockIdx.y * 64, b = blockIdx.z;
    const float* xp = x + (size_t)b * CIN * NPOS;
    int t = threadIdx.x;
    int lr = t >> 4;
    int lc4 = (t & 15) * 4;
    for (int p = 0; p < 4; ++p) {
        int c = lr + p * 16;
        f32x4 v = *reinterpret_cast<const f32x4*>(xp + (size_t)(c0 + c) * NPOS + n0 + lc4);
        tile[c][lc4 + 0] = v[0]; tile[c][lc4 + 1] = v[1];
        tile[c][lc4 + 2] = v[2]; tile[c][lc4 + 3] = v[3];
    }
    __syncthreads();
    bf16* xtp = xT + (size_t)b * NPOS * CIN;
    int cc = (t & 15) * 4;
    for (int p = 0; p < 4; ++p) {
        int n = (t >> 4) + p * 16;
        bf16x4 o;
        o[0] = (bf16)tile[cc + 0][n]; o[1] = (bf16)tile[cc + 1][n];
        o[2] = (bf16)tile[cc + 2][n]; o[3] = (bf16)tile[cc + 3][n];
        *reinterpret_cast<bf16x4*>(xtp + (size_t)(n0 + n) * CIN + c0 + cc) = o;
    }
}

// ---------------------------------------------------------------------------
// K1: q/k/v = W @ x + b.  grid (32 ntile, 3 which, B).  (r6-proven body.)
// ---------------------------------------------------------------------------
__global__ __launch_bounds__(256) void k_qkv(
    const float* __restrict__ Wq, const float* __restrict__ Wk, const float* __restrict__ Wv,
    const float* __restrict__ bq, const float* __restrict__ bk, const float* __restrict__ bv,
    const bf16* __restrict__ xT, bf16* __restrict__ qT, bf16* __restrict__ kT,
    bf16* __restrict__ vC) {
    __shared__ __align__(16) char a_lds[128 * 128];
    __shared__ __align__(16) char b_lds[128 * 128];
    int n0 = blockIdx.x * 128, which = blockIdx.y, b = blockIdx.z;
    const float* W    = which == 0 ? Wq : (which == 1 ? Wk : Wv);
    const float* bias = which == 0 ? bq : (which == 1 ? bk : bv);
    int t = threadIdx.x, lane = t & 63, w = t >> 6, wy = w >> 1, wx = w & 1;
    const bf16* xb = xT + (size_t)b * NPOS * CIN;

    f32x4 acc[4][4] = {};
    for (int k0 = 0; k0 < 256; k0 += 64) {
        __syncthreads();
        for (int i = 0; i < 8; ++i) {
            int idx = t + i * 256;
            int row = idx >> 4, c4 = (idx & 15) * 4;
            f32x4 v = *reinterpret_cast<const f32x4*>(W + (size_t)row * CIN + k0 + c4);
            bf16x4 o; o[0] = (bf16)v[0]; o[1] = (bf16)v[1]; o[2] = (bf16)v[2]; o[3] = (bf16)v[3];
            *reinterpret_cast<bf16x4*>(a_lds + swz128(row, c4 * 2)) = o;
        }
        for (int i = 0; i < 4; ++i) {
            int idx = t + i * 256;
            int row = idx >> 3, cb = (idx & 7) * 16;
            bf16x8 vv = *reinterpret_cast<const bf16x8*>(xb + (size_t)(n0 + row) * CIN + k0 + cb / 2);
            *reinterpret_cast<bf16x8*>(b_lds + swz128(row, cb)) = vv;
        }
        __syncthreads();
        for (int ks = 0; ks < 2; ++ks) {
            int kb = ks * 64 + (lane >> 4) * 16;
            bf16x8 af[4], bfr[4];
            for (int i = 0; i < 4; ++i)
                af[i] = *reinterpret_cast<const bf16x8*>(a_lds + swz128(wy * 64 + i * 16 + (lane & 15), kb));
            for (int j = 0; j < 4; ++j)
                bfr[j] = *reinterpret_cast<const bf16x8*>(b_lds + swz128(wx * 64 + j * 16 + (lane & 15), kb));
            for (int i = 0; i < 4; ++i)
                for (int j = 0; j < 4; ++j)
                    acc[i][j] = MFMA16(af[i], bfr[j], acc[i][j]);
        }
    }
    int rg = lane >> 4, cl = lane & 15;
    for (int i = 0; i < 4; ++i) {
        int ch0 = wy * 64 + i * 16 + rg * 4;
        f32x4 bv4 = *reinterpret_cast<const f32x4*>(bias + ch0);
        for (int j = 0; j < 4; ++j) {
            int n = n0 + wx * 64 + j * 16 + cl;
            f32x4 d = acc[i][j];
            for (int r = 0; r < 4; ++r) d[r] += bv4[r];
            if (which == 2) {
                for (int r = 0; r < 4; ++r)
                    vC[((size_t)b * CMID + ch0 + r) * NPOS + n] = (bf16)d[r];
            } else {
                bf16x4 o; o[0] = (bf16)d[0]; o[1] = (bf16)d[1]; o[2] = (bf16)d[2]; o[3] = (bf16)d[3];
                bf16* dst = (which == 0 ? qT : kT);
                *reinterpret_cast<bf16x4*>(dst + ((size_t)b * NPOS + n) * CMID + ch0) = o;
            }
        }
    }
}

// ---------------------------------------------------------------------------
// K2: zpart[mq][b][n] = sum_{m in eighth mq} exp(S[n,m]).
// Flat grid 1024, XCD-decoded (mq = xcd): q-streams L2-resident.  DMA dbuf.
// Plain launch_bounds (no min-waves VGPR cap — r8/r10 lesson).
// ---------------------------------------------------------------------------
__global__ __launch_bounds__(256) void k_zrow(const bf16* __restrict__ qT,
                                              const bf16* __restrict__ kT,
                                              float* __restrict__ zpart) {
    __shared__ __align__(16) char q_lds[2][64 * 256];  // [64 m][128 c] swz256
    int l = blockIdx.x;
    int xcd = l & 7, slot = l >> 3;
    int mq = xcd, b = slot & 3;
    int n0 = (slot >> 2) * 128;
    int t = threadIdx.x, lane = t & 63, w = t >> 6;
    int cl = lane & 15, g = lane >> 4;
    const bf16* qb = qT + (size_t)b * NPOS * CMID;
    const bf16* kb = kT + (size_t)b * NPOS * CMID;

    auto stage_q = [&](int buf, int m0) {
        #pragma unroll
        for (int i = 0; i < 4; ++i) {
            int lc = (w * 4 + i) * 64 + lane;
            int r = lc >> 4, p = lc & 15;
            GLDS(qb + (size_t)(m0 + r) * CMID + ((p ^ (r & 7)) << 3),
                 q_lds[buf] + (w * 4 + i) * 1024);
        }
    };

    bf16x8 kreg[2][4];
    for (int jn = 0; jn < 2; ++jn)
        for (int ks = 0; ks < 4; ++ks)
            kreg[jn][ks] = *reinterpret_cast<const bf16x8*>(
                kb + (size_t)(n0 + w * 32 + jn * 16 + cl) * CMID + ks * 32 + g * 8);

    int mbeg = mq * (NPOS / 8);
    stage_q(0, mbeg);
    asm volatile("s_waitcnt vmcnt(0)" ::: "memory");
    __syncthreads();
    int cur = 0;
    float zacc[2] = {0.f, 0.f};
    for (int m0 = mbeg; m0 < mbeg + NPOS / 8; m0 += 64) {
        if (m0 + 64 < mbeg + NPOS / 8) stage_q(cur ^ 1, m0 + 64);
        f32x4 acc[4][2] = {};
        __builtin_amdgcn_s_setprio(1);
        for (int ks = 0; ks < 4; ++ks) {
            bf16x8 qf[4];
            for (int im = 0; im < 4; ++im)
                qf[im] = *reinterpret_cast<const bf16x8*>(q_lds[cur] + swz256(im * 16 + cl, ks * 64 + g * 16));
            for (int im = 0; im < 4; ++im)
                for (int jn = 0; jn < 2; ++jn)
                    acc[im][jn] = MFMA16(qf[im], kreg[jn][ks], acc[im][jn]);
        }
        __builtin_amdgcn_s_setprio(0);
        for (int im = 0; im < 4; ++im)
            for (int jn = 0; jn < 2; ++jn)
                for (int r = 0; r < 4; ++r)
                    zacc[jn] += __expf(acc[im][jn][r]);
        __syncthreads();
        cur ^= 1;
    }
    for (int jn = 0; jn < 2; ++jn) {
        zacc[jn] += __shfl_xor(zacc[jn], 16);
        zacc[jn] += __shfl_xor(zacc[jn], 32);
    }
    if (g == 0) {
        float* zp = zpart + ((size_t)mq * BATCH + b) * NPOS;
        zp[n0 + w * 32 + cl]      = zacc[0];
        zp[n0 + w * 32 + 16 + cl] = zacc[1];
    }
}

// ---------------------------------------------------------------------------
// K3: invZ = 1 / sum_{s<8} zpart[s].
// ---------------------------------------------------------------------------
__global__ __launch_bounds__(256) void k_rcp(const float* __restrict__ zpart,
                                             float* __restrict__ invZ) {
    int i = (blockIdx.x * 256 + threadIdx.x) * 4;
    f32x4 s = {0.f, 0.f, 0.f, 0.f};
    for (int p = 0; p < 8; ++p) {
        f32x4 a = *reinterpret_cast<const f32x4*>(zpart + (size_t)p * BATCH * NPOS + i);
        for (int r = 0; r < 4; ++r) s[r] += a[r];
    }
    f32x4 o;
    for (int r = 0; r < 4; ++r) o[r] = 1.f / s[r];
    *reinterpret_cast<f32x4*>(invZ + i) = o;
}

// ---------------------------------------------------------------------------
// K3b: vC[c,n] *= invZ[n]  (in-place).
// ---------------------------------------------------------------------------
__global__ __launch_bounds__(256) void k_vscale(bf16* __restrict__ vC,
                                                const float* __restrict__ invZ) {
    int idx = blockIdx.x * 256 + threadIdx.x;
    int b = idx >> 16;
    int n8 = idx & (NPOS / 8 - 1);
    bf16x8 v = *reinterpret_cast<const bf16x8*>(vC + (size_t)idx * 8);
    const float* iz = invZ + (size_t)b * NPOS + n8 * 8;
    f32x4 i0 = *reinterpret_cast<const f32x4*>(iz);
    f32x4 i1 = *reinterpret_cast<const f32x4*>(iz + 4);
    bf16x8 o;
    for (int r = 0; r < 4; ++r) {
        o[r]     = (bf16)((float)v[r]     * i0[r]);
        o[r + 4] = (bf16)((float)v[r + 4] * i1[r]);
    }
    *reinterpret_cast<bf16x8*>(vC + (size_t)idx * 8) = o;
}

// ---------------------------------------------------------------------------
// K4: y[m][c] = sum_n exp(S[n,m]) vs[c,n]  (vs = invZ-prescaled v).
// r9 dataflow, 512-thread blocks: 8 waves x 16m each -> per-wave VGPR ~halved
// (acc2 32 + qreg 16; total <=~120) so 2 blocks/CU = 16 waves/CU (double r9)
// WITHOUT any launch_bounds VGPR cap.  LDS 80KB: k dbuf 32 + v dbuf 32 +
// P 16 ([128m][64n] swz128, wave-private rows).  XCD decode (FETCH 12MB,
// r9-proven).  No mid barrier; 1 barrier/step.
// ---------------------------------------------------------------------------
__global__ __launch_bounds__(512) void k_attn(const bf16* __restrict__ qT,
                                              const bf16* __restrict__ kT,
                                              const bf16* __restrict__ vS,
                                              bf16* __restrict__ ys) {
    __shared__ __align__(16) char k_lds[2][64 * 256];   // [64 n][128 c] swz256
    __shared__ __align__(16) char v_lds[2][128 * 128];  // [128 c][64 n] swz128
    __shared__ __align__(16) char p_lds[128 * 128];     // [128 m][64 n] swz128
    int l = blockIdx.x;
    int xcd = l & 7, slot = l >> 3;
    int combo = xcd * 2 + (slot & 1);                // 16 combos (nq,b), 2/XCD
    int m0 = (slot >> 1) * 128;
    int nq = combo >> 2, b = combo & 3;
    int t = threadIdx.x, lane = t & 63, w = t >> 6;  // w: 0..7
    int cl = lane & 15, g = lane >> 4;
    const bf16* qb = qT + (size_t)b * NPOS * CMID;
    const bf16* kb = kT + (size_t)b * NPOS * CMID;
    const bf16* vb = vS + (size_t)b * CMID * NPOS;

    auto stage_kv = [&](int buf, int n0) {
        #pragma unroll
        for (int i = 0; i < 2; ++i) {
            int lc = (w * 2 + i) * 64 + lane;        // 16B-chunk idx 0..1023
            int kr = lc >> 4, kp = lc & 15;          // k: 16 chunks/row
            GLDS(kb + (size_t)(n0 + kr) * CMID + ((kp ^ (kr & 7)) << 3),
                 k_lds[buf] + (w * 2 + i) * 1024);
            int vr = lc >> 3, vp = lc & 7;           // v: 8 chunks/row
            GLDS(vb + (size_t)vr * NPOS + n0 + ((vp ^ (vr & 7)) << 3),
                 v_lds[buf] + (w * 2 + i) * 1024);
        }
    };

    // q fragments (B-operand): wave owns m-cols m0 + w*16 + cl
    bf16x8 qreg[4];
    for (int ks = 0; ks < 4; ++ks)
        qreg[ks] = *reinterpret_cast<const bf16x8*>(
            qb + (size_t)(m0 + w * 16 + cl) * CMID + ks * 32 + g * 8);

    f32x4 acc2[8] = {};                              // y[m: wave's 16][c: 128]
    int nbeg = nq * (NPOS / NQATT);
    stage_kv(0, nbeg);
    asm volatile("s_waitcnt vmcnt(0)" ::: "memory");
    __syncthreads();
    int cur = 0;
    for (int s = 0; s < NPOS / NQATT / 64; ++s) {
        int n0 = nbeg + s * 64;
        if (s + 1 < NPOS / NQATT / 64) stage_kv(cur ^ 1, n0 + 64);
        // S^T: acc1[in] = D[n = in*16+g*4+r][m = w*16+cl]
        f32x4 acc1[4] = {};
        __builtin_amdgcn_s_setprio(1);
        for (int ks = 0; ks < 4; ++ks) {
            bf16x8 kf[4];
            for (int in = 0; in < 4; ++in)
                kf[in] = *reinterpret_cast<const bf16x8*>(k_lds[cur] + swz256(in * 16 + cl, ks * 64 + g * 16));
            for (int in = 0; in < 4; ++in)
                acc1[in] = MFMA16(kf[in], qreg[ks], acc1[in]);
        }
        __builtin_amdgcn_s_setprio(0);
        // P^T[m][n] = exp(S), wave-private rows m = w*16..w*16+15.
        for (int in = 0; in < 4; ++in) {
            bf16x4 o;
            for (int r = 0; r < 4; ++r) o[r] = (bf16)__expf(acc1[in][r]);
            *reinterpret_cast<bf16x4*>(p_lds + swz128(w * 16 + cl, in * 32 + g * 8)) = o;
        }
        // PV m-split: A = own P row-block (16m), B = all v c-tiles.
        __builtin_amdgcn_s_setprio(1);
        for (int s32 = 0; s32 < 2; ++s32) {
            bf16x8 af = *reinterpret_cast<const bf16x8*>(p_lds + swz128(w * 16 + cl, s32 * 64 + g * 16));
            for (int j = 0; j < 8; ++j) {
                bf16x8 vf = *reinterpret_cast<const bf16x8*>(v_lds[cur] + swz128(j * 16 + cl, s32 * 64 + g * 16));
                acc2[j] = MFMA16(af, vf, acc2[j]);
            }
        }
        __builtin_amdgcn_s_setprio(0);
        __syncthreads();   // staged buf ready (vm drained) + reads of cur done
        cur ^= 1;
    }
    bf16* yb = ys + (size_t)nq * BATCH * NPOS * CMID
             + ((size_t)b * NPOS + m0) * CMID;
    for (int j = 0; j < 8; ++j) {
        int c = j * 16 + cl;
        for (int r = 0; r < 4; ++r) {
            int m = w * 16 + g * 4 + r;
            yb[(size_t)m * CMID + c] = (bf16)acc2[j][r];
        }
    }
}

// ---------------------------------------------------------------------------
// K5: out = (Ww @ sum_{s<ns} y_s + bw)*inv + add + x. grid (64 mtile,2 ot,B).
// ---------------------------------------------------------------------------
__global__ __launch_bounds__(256) void k_out(
    const float* __restrict__ Ww, const float* __restrict__ bw,
    const float* __restrict__ gamma, const float* __restrict__ beta,
    const float* __restrict__ mean, const float* __restrict__ var,
    const bf16* __restrict__ ys, int ns,
    const float* __restrict__ x, float* __restrict__ out) {
    __shared__ __align__(16) char a_lds[128 * 128];  // [128 o][64 c] swz
    __shared__ __align__(16) char b_lds[64 * 128];   // [64 m][64 c] swz
    int m0 = blockIdx.x * 64, o0 = blockIdx.y * 128, b = blockIdx.z;
    int t = threadIdx.x, lane = t & 63, w = t >> 6, wy = w >> 1, wx = w & 1;
    const size_t SL = (size_t)BATCH * NPOS * CMID;   // slice stride (elems)
    f32x4 acc[4][2] = {};
    for (int k0 = 0; k0 < 128; k0 += 64) {
        __syncthreads();
        for (int i = 0; i < 8; ++i) {
            int idx = t + i * 256, row = idx >> 4, c4 = (idx & 15) * 4;
            f32x4 v = *reinterpret_cast<const f32x4*>(Ww + (size_t)(o0 + row) * CMID + k0 + c4);
            bf16x4 o; o[0] = (bf16)v[0]; o[1] = (bf16)v[1]; o[2] = (bf16)v[2]; o[3] = (bf16)v[3];
            *reinterpret_cast<bf16x4*>(a_lds + swz128(row, c4 * 2)) = o;
        }
        for (int i = 0; i < 4; ++i) {
            int idx = t + i * 256, row = idx >> 4, c4 = (idx & 15) * 4;
            size_t yoff = ((size_t)b * NPOS + m0 + row) * CMID + k0 + c4;
            float sacc[4] = {0.f, 0.f, 0.f, 0.f};
            for (int p = 0; p < ns; ++p) {
                bf16x4 a = *reinterpret_cast<const bf16x4*>(ys + (size_t)p * SL + yoff);
                for (int r = 0; r < 4; ++r) sacc[r] += (float)a[r];
            }
            bf16x4 o;
            for (int r = 0; r < 4; ++r) o[r] = (bf16)sacc[r];
            *reinterpret_cast<bf16x4*>(b_lds + swz128(row, c4 * 2)) = o;
        }
        __syncthreads();
        for (int ks = 0; ks < 2; ++ks) {
            int kb = ks * 64 + (lane >> 4) * 16;
            bf16x8 af[4], bfr[2];
            for (int i = 0; i < 4; ++i)
                af[i] = *reinterpret_cast<const bf16x8*>(a_lds + swz128(wy * 64 + i * 16 + (lane & 15), kb));
            for (int j = 0; j < 2; ++j)
                bfr[j] = *reinterpret_cast<const bf16x8*>(b_lds + swz128(wx * 32 + j * 16 + (lane & 15), kb));
            for (int i = 0; i < 4; ++i)
                for (int j = 0; j < 2; ++j)
                    acc[i][j] = MFMA16(af[i], bfr[j], acc[i][j]);
        }
    }
    int rg = lane >> 4, cl = lane & 15;
    const float* xb = x + (size_t)b * CIN * NPOS;
    float* ob = out + (size_t)b * CIN * NPOS;
    for (int i = 0; i < 4; ++i) {
        int och0 = o0 + wy * 64 + i * 16 + rg * 4;
        f32x4 gg = *reinterpret_cast<const f32x4*>(gamma + och0);
        f32x4 be = *reinterpret_cast<const f32x4*>(beta + och0);
        f32x4 mu = *reinterpret_cast<const f32x4*>(mean + och0);
        f32x4 va = *reinterpret_cast<const f32x4*>(var + och0);
        f32x4 bb = *reinterpret_cast<const f32x4*>(bw + och0);
        float invv[4], addv[4];
        for (int r = 0; r < 4; ++r) {
            invv[r] = gg[r] / sqrtf(va[r] + EPS);
            addv[r] = be[r] - mu[r] * invv[r];
        }
        for (int j = 0; j < 2; ++j) {
            int m = m0 + wx * 32 + j * 16 + cl;
            for (int r = 0; r < 4; ++r) {
                float z = (acc[i][j][r] + bb[r]) * invv[r] + addv[r];
                ob[(size_t)(och0 + r) * NPOS + m] = z + xb[(size_t)(och0 + r) * NPOS + m];
            }
        }
    }
}

// ---------------------------------------------------------------------------
extern "C" void kernel_launch(void* const* d_in, const int* in_sizes, int n_in,
                              void* d_out, int out_size, void* d_ws, size_t ws_size,
                              hipStream_t stream) {
    const float* x     = (const float*)d_in[0];
    const float* Wq    = (const float*)d_in[1];
    const float* bq    = (const float*)d_in[2];
    const float* Wk    = (const float*)d_in[3];
    const float* bk    = (const float*)d_in[4];
    const float* Wv    = (const float*)d_in[5];
    const float* bv    = (const float*)d_in[6];
    const float* Ww    = (const float*)d_in[7];
    const float* bw    = (const float*)d_in[8];
    const float* gamma = (const float*)d_in[9];
    const float* beta  = (const float*)d_in[10];
    const float* mean  = (const float*)d_in[11];
    const float* var   = (const float*)d_in[12];
    float* out = (float*)d_out;

    const size_t slice = (size_t)BATCH * NPOS * CMID * 2;   // 4 MB

    char* p = (char*)d_ws;
    bf16* ys = (bf16*)p;        p += (size_t)NQATT * slice; // 16 MB (4 slices)
    bf16* qT = (bf16*)p;        p += slice;                 // 4 MB
    bf16* kT = (bf16*)p;        p += slice;                 // 4 MB
    bf16* vC = (bf16*)p;        p += slice;                 // 4 MB
    float* zpart = (float*)p;   p += (size_t)8 * BATCH * NPOS * 4;  // 512 KB
    float* invZ = (float*)p;                                        // 64 KB
    bf16* xT = (bf16*)d_ws;     // overlays ys[0..3]; dead before k_attn writes

    kt_transpose<<<dim3(NPOS / 64, CIN / 64, BATCH), 256, 0, stream>>>(x, xT);
    k_qkv<<<dim3(NPOS / 128, 3, BATCH), 256, 0, stream>>>(Wq, Wk, Wv, bq, bk, bv, xT, qT, kT, vC);
    k_zrow<<<dim3(1024), 256, 0, stream>>>(qT, kT, zpart);
    k_rcp<<<dim3(BATCH * NPOS / 1024), 256, 0, stream>>>(zpart, invZ);
    k_vscale<<<dim3(BATCH * CMID * NPOS / 8 / 256), 256, 0, stream>>>(vC, invZ);
    k_attn<<<dim3(512), 512, 0, stream>>>(qT, kT, vC, ys);
    k_out<<<dim3(NPOS / 64, 2, BATCH), 256, 0, stream>>>(Ww, bw, gamma, beta, mean, var, ys, NQATT, x, out);
}

// Round 13
// 105.459 us; speedup vs baseline: 2.2386x; 1.0443x over previous
//
#include <hip/hip_runtime.h>
#include <hip/hip_bf16.h>

#define BATCH 4
#define CIN   256
#define CMID  128
#define NPOS  4096
#define EPS   1e-5f
#define NQATT 4

typedef __bf16 bf16;
typedef __attribute__((ext_vector_type(8))) __bf16 bf16x8;
typedef __attribute__((ext_vector_type(4))) __bf16 bf16x4;
typedef __attribute__((ext_vector_type(4))) float  f32x4;

#define MFMA16(a, b, c) __builtin_amdgcn_mfma_f32_16x16x32_bf16((a), (b), (c), 0, 0, 0)

// async global->LDS DMA, 16B per lane, dest = wave-uniform base + lane*16
#define GLDS(gsrc, ldst) \
    __builtin_amdgcn_global_load_lds( \
        (const __attribute__((address_space(1))) void*)(gsrc), \
        (__attribute__((address_space(3))) void*)(ldst), 16, 0, 0)

// XOR swizzle, 256B rows (16 chunks/row): chunk ^= row&7.
__device__ __forceinline__ int swz256(int row, int colb) {
    return row * 256 + ((((colb >> 4) ^ (row & 7)) << 4) | (colb & 15));
}
// XOR swizzle, 128B rows (8 chunks/row): chunk ^= row&7.
__device__ __forceinline__ int swz128(int row, int colb) {
    return row * 128 + ((((colb >> 4) ^ (row & 7)) << 4) | (colb & 15));
}
// 64B-row tiles ([rows][32 n] bf16): phys chunk = row*4 + (n4 ^ ((row>>1)&3)).
__device__ __forceinline__ int cswz(int row, int n4) {
    return (row * 4 + (n4 ^ ((row >> 1) & 3))) * 16;
}

// ---------------------------------------------------------------------------
// KT: x [B][CIN][N] f32  ->  xT [B][N][CIN] bf16   (LDS 64x64 tile transpose)
// ~5.7 TB/s measured — near HBM roofline for this op.
// ---------------------------------------------------------------------------
__global__ __launch_bounds__(256) void kt_transpose(const float* __restrict__ x,
                                                    bf16* __restrict__ xT) {
    __shared__ float tile[64][65];
    int n0 = blockIdx.x * 64, c0 = blockIdx.y * 64, b = blockIdx.z;
    const float* xp = x + (size_t)b * CIN * NPOS;
    int t = threadIdx.x;
    int lr = t >> 4;
    int lc4 = (t & 15) * 4;
    for (int p = 0; p < 4; ++p) {
        int c = lr + p * 16;
        f32x4 v = *reinterpret_cast<const f32x4*>(xp + (size_t)(c0 + c) * NPOS + n0 + lc4);
        tile[c][lc4 + 0] = v[0]; tile[c][lc4 + 1] = v[1];
        tile[c][lc4 + 2] = v[2]; tile[c][lc4 + 3] = v[3];
    }
    __syncthreads();
    bf16* xtp = xT + (size_t)b * NPOS * CIN;
    int cc = (t & 15) * 4;
    for (int p = 0; p < 4; ++p) {
        int n = (t >> 4) + p * 16;
        bf16x4 o;
        o[0] = (bf16)tile[cc + 0][n]; o[1] = (bf16)tile[cc + 1][n];
        o[2] = (bf16)tile[cc + 2][n]; o[3] = (bf16)tile[cc + 3][n];
        *reinterpret_cast<bf16x4*>(xtp + (size_t)(n0 + n) * CIN + c0 + cc) = o;
    }
}

// ---------------------------------------------------------------------------
// K1: q/k/v = W @ x + b.  grid (32 ntile, 3 which, B).  (r6-proven body.)
// ---------------------------------------------------------------------------
__global__ __launch_bounds__(256) void k_qkv(
    const float* __restrict__ Wq, const float* __restrict__ Wk, const float* __restrict__ Wv,
    const float* __restrict__ bq, const float* __restrict__ bk, const float* __restrict__ bv,
    const bf16* __restrict__ xT, bf16* __restrict__ qT, bf16* __restrict__ kT,
    bf16* __restrict__ vC) {
    __shared__ __align__(16) char a_lds[128 * 128];
    __shared__ __align__(16) char b_lds[128 * 128];
    int n0 = blockIdx.x * 128, which = blockIdx.y, b = blockIdx.z;
    const float* W    = which == 0 ? Wq : (which == 1 ? Wk : Wv);
    const float* bias = which == 0 ? bq : (which == 1 ? bk : bv);
    int t = threadIdx.x, lane = t & 63, w = t >> 6, wy = w >> 1, wx = w & 1;
    const bf16* xb = xT + (size_t)b * NPOS * CIN;

    f32x4 acc[4][4] = {};
    for (int k0 = 0; k0 < 256; k0 += 64) {
        __syncthreads();
        for (int i = 0; i < 8; ++i) {
            int idx = t + i * 256;
            int row = idx >> 4, c4 = (idx & 15) * 4;
            f32x4 v = *reinterpret_cast<const f32x4*>(W + (size_t)row * CIN + k0 + c4);
            bf16x4 o; o[0] = (bf16)v[0]; o[1] = (bf16)v[1]; o[2] = (bf16)v[2]; o[3] = (bf16)v[3];
            *reinterpret_cast<bf16x4*>(a_lds + swz128(row, c4 * 2)) = o;
        }
        for (int i = 0; i < 4; ++i) {
            int idx = t + i * 256;
            int row = idx >> 3, cb = (idx & 7) * 16;
            bf16x8 vv = *reinterpret_cast<const bf16x8*>(xb + (size_t)(n0 + row) * CIN + k0 + cb / 2);
            *reinterpret_cast<bf16x8*>(b_lds + swz128(row, cb)) = vv;
        }
        __syncthreads();
        for (int ks = 0; ks < 2; ++ks) {
            int kb = ks * 64 + (lane >> 4) * 16;
            bf16x8 af[4], bfr[4];
            for (int i = 0; i < 4; ++i)
                af[i] = *reinterpret_cast<const bf16x8*>(a_lds + swz128(wy * 64 + i * 16 + (lane & 15), kb));
            for (int j = 0; j < 4; ++j)
                bfr[j] = *reinterpret_cast<const bf16x8*>(b_lds + swz128(wx * 64 + j * 16 + (lane & 15), kb));
            for (int i = 0; i < 4; ++i)
                for (int j = 0; j < 4; ++j)
                    acc[i][j] = MFMA16(af[i], bfr[j], acc[i][j]);
        }
    }
    int rg = lane >> 4, cl = lane & 15;
    for (int i = 0; i < 4; ++i) {
        int ch0 = wy * 64 + i * 16 + rg * 4;
        f32x4 bv4 = *reinterpret_cast<const f32x4*>(bias + ch0);
        for (int j = 0; j < 4; ++j) {
            int n = n0 + wx * 64 + j * 16 + cl;
            f32x4 d = acc[i][j];
            for (int r = 0; r < 4; ++r) d[r] += bv4[r];
            if (which == 2) {
                for (int r = 0; r < 4; ++r)
                    vC[((size_t)b * CMID + ch0 + r) * NPOS + n] = (bf16)d[r];
            } else {
                bf16x4 o; o[0] = (bf16)d[0]; o[1] = (bf16)d[1]; o[2] = (bf16)d[2]; o[3] = (bf16)d[3];
                bf16* dst = (which == 0 ? qT : kT);
                *reinterpret_cast<bf16x4*>(dst + ((size_t)b * NPOS + n) * CMID + ch0) = o;
            }
        }
    }
}

// ---------------------------------------------------------------------------
// K2: zpart[mq][b][n] = sum_{m in eighth mq} exp(S[n,m]).
// Flat grid 1024, XCD-decoded (mq = xcd): q-streams L2-resident.  DMA dbuf,
// 4 blocks/CU (32KB LDS, r6-proven at this occupancy).
// ---------------------------------------------------------------------------
__global__ __launch_bounds__(256, 4) void k_zrow(const bf16* __restrict__ qT,
                                                 const bf16* __restrict__ kT,
                                                 float* __restrict__ zpart) {
    __shared__ __align__(16) char q_lds[2][64 * 256];  // [64 m][128 c] swz256
    int l = blockIdx.x;
    int xcd = l & 7, slot = l >> 3;
    int mq = xcd, b = slot & 3;
    int n0 = (slot >> 2) * 128;
    int t = threadIdx.x, lane = t & 63, w = t >> 6;
    int cl = lane & 15, g = lane >> 4;
    const bf16* qb = qT + (size_t)b * NPOS * CMID;
    const bf16* kb = kT + (size_t)b * NPOS * CMID;

    auto stage_q = [&](int buf, int m0) {
        #pragma unroll
        for (int i = 0; i < 4; ++i) {
            int lc = (w * 4 + i) * 64 + lane;
            int r = lc >> 4, p = lc & 15;
            GLDS(qb + (size_t)(m0 + r) * CMID + ((p ^ (r & 7)) << 3),
                 q_lds[buf] + (w * 4 + i) * 1024);
        }
    };

    bf16x8 kreg[2][4];
    for (int jn = 0; jn < 2; ++jn)
        for (int ks = 0; ks < 4; ++ks)
            kreg[jn][ks] = *reinterpret_cast<const bf16x8*>(
                kb + (size_t)(n0 + w * 32 + jn * 16 + cl) * CMID + ks * 32 + g * 8);

    int mbeg = mq * (NPOS / 8);
    stage_q(0, mbeg);
    asm volatile("s_waitcnt vmcnt(0)" ::: "memory");
    __syncthreads();
    int cur = 0;
    float zacc[2] = {0.f, 0.f};
    for (int m0 = mbeg; m0 < mbeg + NPOS / 8; m0 += 64) {
        if (m0 + 64 < mbeg + NPOS / 8) stage_q(cur ^ 1, m0 + 64);
        f32x4 acc[4][2] = {};
        __builtin_amdgcn_s_setprio(1);
        for (int ks = 0; ks < 4; ++ks) {
            bf16x8 qf[4];
            for (int im = 0; im < 4; ++im)
                qf[im] = *reinterpret_cast<const bf16x8*>(q_lds[cur] + swz256(im * 16 + cl, ks * 64 + g * 16));
            for (int im = 0; im < 4; ++im)
                for (int jn = 0; jn < 2; ++jn)
                    acc[im][jn] = MFMA16(qf[im], kreg[jn][ks], acc[im][jn]);
        }
        __builtin_amdgcn_s_setprio(0);
        for (int im = 0; im < 4; ++im)
            for (int jn = 0; jn < 2; ++jn)
                for (int r = 0; r < 4; ++r)
                    zacc[jn] += __expf(acc[im][jn][r]);
        __syncthreads();
        cur ^= 1;
    }
    for (int jn = 0; jn < 2; ++jn) {
        zacc[jn] += __shfl_xor(zacc[jn], 16);
        zacc[jn] += __shfl_xor(zacc[jn], 32);
    }
    if (g == 0) {
        float* zp = zpart + ((size_t)mq * BATCH + b) * NPOS;
        zp[n0 + w * 32 + cl]      = zacc[0];
        zp[n0 + w * 32 + 16 + cl] = zacc[1];
    }
}

// ---------------------------------------------------------------------------
// K3: invZ = 1 / sum_{s<8} zpart[s].
// ---------------------------------------------------------------------------
__global__ __launch_bounds__(256) void k_rcp(const float* __restrict__ zpart,
                                             float* __restrict__ invZ) {
    int i = (blockIdx.x * 256 + threadIdx.x) * 4;
    f32x4 s = {0.f, 0.f, 0.f, 0.f};
    for (int p = 0; p < 8; ++p) {
        f32x4 a = *reinterpret_cast<const f32x4*>(zpart + (size_t)p * BATCH * NPOS + i);
        for (int r = 0; r < 4; ++r) s[r] += a[r];
    }
    f32x4 o;
    for (int r = 0; r < 4; ++r) o[r] = 1.f / s[r];
    *reinterpret_cast<f32x4*>(invZ + i) = o;
}

// ---------------------------------------------------------------------------
// K3b: vC[c,n] *= invZ[n]  (in-place).
// ---------------------------------------------------------------------------
__global__ __launch_bounds__(256) void k_vscale(bf16* __restrict__ vC,
                                                const float* __restrict__ invZ) {
    int idx = blockIdx.x * 256 + threadIdx.x;
    int b = idx >> 16;
    int n8 = idx & (NPOS / 8 - 1);
    bf16x8 v = *reinterpret_cast<const bf16x8*>(vC + (size_t)idx * 8);
    const float* iz = invZ + (size_t)b * NPOS + n8 * 8;
    f32x4 i0 = *reinterpret_cast<const f32x4*>(iz);
    f32x4 i1 = *reinterpret_cast<const f32x4*>(iz + 4);
    bf16x8 o;
    for (int r = 0; r < 4; ++r) {
        o[r]     = (bf16)((float)v[r]     * i0[r]);
        o[r + 4] = (bf16)((float)v[r + 4] * i1[r]);
    }
    *reinterpret_cast<bf16x8*>(vC + (size_t)idx * 8) = o;
}

// ---------------------------------------------------------------------------
// K4: y[m][c] = sum_n exp(S[n,m]) vs[c,n]  (vs = invZ-prescaled v).
// r9-measured-best body (42.7us): flat grid 512, XCD-decoded so each XCD owns
// exactly 2 (nq,b) k/v streams (L2-resident, FETCH 12.3MB).  q-frags in regs;
// k/v DMA dbuf LDS (80KB, 2 blocks/CU); m-split PV keeps P wave-private (no
// mid barrier); setprio around MFMA clusters.
// ---------------------------------------------------------------------------
__global__ __launch_bounds__(256, 2) void k_attn(const bf16* __restrict__ qT,
                                                 const bf16* __restrict__ kT,
                                                 const bf16* __restrict__ vS,
                                                 bf16* __restrict__ ys) {
    __shared__ __align__(16) char k_lds[2][64 * 256];   // [64 n][128 c] swz256
    __shared__ __align__(16) char v_lds[2][128 * 128];  // [128 c][64 n] swz128
    __shared__ __align__(16) char p_lds[128 * 128];     // [128 m][64 n] swz128
    int l = blockIdx.x;
    int xcd = l & 7, slot = l >> 3;
    int combo = xcd * 2 + (slot & 1);                // 16 combos (nq,b), 2/XCD
    int m0 = (slot >> 1) * 128;
    int nq = combo >> 2, b = combo & 3;
    int t = threadIdx.x, lane = t & 63, w = t >> 6;
    int cl = lane & 15, g = lane >> 4;
    const bf16* qb = qT + (size_t)b * NPOS * CMID;
    const bf16* kb = kT + (size_t)b * NPOS * CMID;
    const bf16* vb = vS + (size_t)b * CMID * NPOS;

    auto stage_kv = [&](int buf, int n0) {
        #pragma unroll
        for (int i = 0; i < 4; ++i) {
            int lc = (w * 4 + i) * 64 + lane;        // 16B-chunk idx in tile
            int kr = lc >> 4, kp = lc & 15;          // k: 16 chunks/row
            GLDS(kb + (size_t)(n0 + kr) * CMID + ((kp ^ (kr & 7)) << 3),
                 k_lds[buf] + (w * 4 + i) * 1024);
            int vr = lc >> 3, vp = lc & 7;           // v: 8 chunks/row
            GLDS(vb + (size_t)vr * NPOS + n0 + ((vp ^ (vr & 7)) << 3),
                 v_lds[buf] + (w * 4 + i) * 1024);
        }
    };

    // q fragments (B-operand): wave owns m-cols m0 + w*32 + jm*16 + cl
    bf16x8 qreg[2][4];
    for (int jm = 0; jm < 2; ++jm)
        for (int ks = 0; ks < 4; ++ks)
            qreg[jm][ks] = *reinterpret_cast<const bf16x8*>(
                qb + (size_t)(m0 + w * 32 + jm * 16 + cl) * CMID + ks * 32 + g * 8);

    f32x4 acc2[2][8] = {};                           // y[m: wave's 32][c: 128]
    int nbeg = nq * (NPOS / NQATT);
    stage_kv(0, nbeg);
    asm volatile("s_waitcnt vmcnt(0)" ::: "memory");
    __syncthreads();
    int cur = 0;
    for (int s = 0; s < NPOS / NQATT / 64; ++s) {
        int n0 = nbeg + s * 64;
        if (s + 1 < NPOS / NQATT / 64) stage_kv(cur ^ 1, n0 + 64);
        // S^T: acc1[in][jm] = D[n = in*16+g*4+r][m = w*32+jm*16+cl]
        f32x4 acc1[4][2] = {};
        __builtin_amdgcn_s_setprio(1);
        for (int ks = 0; ks < 4; ++ks) {
            bf16x8 kf[4];
            for (int in = 0; in < 4; ++in)
                kf[in] = *reinterpret_cast<const bf16x8*>(k_lds[cur] + swz256(in * 16 + cl, ks * 64 + g * 16));
            for (int in = 0; in < 4; ++in)
                for (int jm = 0; jm < 2; ++jm)
                    acc1[in][jm] = MFMA16(kf[in], qreg[jm][ks], acc1[in][jm]);
        }
        __builtin_amdgcn_s_setprio(0);
        // P^T[m][n] = exp(S), wave-private rows (lane writes 4 consecutive n).
        for (int in = 0; in < 4; ++in)
            for (int jm = 0; jm < 2; ++jm) {
                bf16x4 o;
                for (int r = 0; r < 4; ++r) o[r] = (bf16)__expf(acc1[in][jm][r]);
                *reinterpret_cast<bf16x4*>(p_lds + swz128(w * 32 + jm * 16 + cl, in * 32 + g * 8)) = o;
            }
        // PV m-split: A = own P rows, B = all v c-tiles. No barrier needed.
        __builtin_amdgcn_s_setprio(1);
        for (int s32 = 0; s32 < 2; ++s32) {
            bf16x8 af[2], vf[8];
            for (int jm = 0; jm < 2; ++jm)
                af[jm] = *reinterpret_cast<const bf16x8*>(p_lds + swz128(w * 32 + jm * 16 + cl, s32 * 64 + g * 16));
            for (int j = 0; j < 8; ++j)
                vf[j] = *reinterpret_cast<const bf16x8*>(v_lds[cur] + swz128(j * 16 + cl, s32 * 64 + g * 16));
            for (int jm = 0; jm < 2; ++jm)
                for (int j = 0; j < 8; ++j)
                    acc2[jm][j] = MFMA16(af[jm], vf[j], acc2[jm][j]);
        }
        __builtin_amdgcn_s_setprio(0);
        __syncthreads();   // staged buf ready (vm drained) + reads of cur done
        cur ^= 1;
    }
    bf16* yb = ys + (size_t)nq * BATCH * NPOS * CMID
             + ((size_t)b * NPOS + m0) * CMID;
    for (int jm = 0; jm < 2; ++jm)
        for (int j = 0; j < 8; ++j) {
            int c = j * 16 + cl;
            for (int r = 0; r < 4; ++r) {
                int m = w * 32 + jm * 16 + g * 4 + r;
                yb[(size_t)m * CMID + c] = (bf16)acc2[jm][j][r];
            }
        }
}

// ---------------------------------------------------------------------------
// K5: out = (Ww @ sum_{s<ns} y_s + bw)*inv + add + x. grid (64 mtile,2 ot,B).
// ---------------------------------------------------------------------------
__global__ __launch_bounds__(256) void k_out(
    const float* __restrict__ Ww, const float* __restrict__ bw,
    const float* __restrict__ gamma, const float* __restrict__ beta,
    const float* __restrict__ mean, const float* __restrict__ var,
    const bf16* __restrict__ ys, int ns,
    const float* __restrict__ x, float* __restrict__ out) {
    __shared__ __align__(16) char a_lds[128 * 128];  // [128 o][64 c] swz
    __shared__ __align__(16) char b_lds[64 * 128];   // [64 m][64 c] swz
    int m0 = blockIdx.x * 64, o0 = blockIdx.y * 128, b = blockIdx.z;
    int t = threadIdx.x, lane = t & 63, w = t >> 6, wy = w >> 1, wx = w & 1;
    const size_t SL = (size_t)BATCH * NPOS * CMID;   // slice stride (elems)
    f32x4 acc[4][2] = {};
    for (int k0 = 0; k0 < 128; k0 += 64) {
        __syncthreads();
        for (int i = 0; i < 8; ++i) {
            int idx = t + i * 256, row = idx >> 4, c4 = (idx & 15) * 4;
            f32x4 v = *reinterpret_cast<const f32x4*>(Ww + (size_t)(o0 + row) * CMID + k0 + c4);
            bf16x4 o; o[0] = (bf16)v[0]; o[1] = (bf16)v[1]; o[2] = (bf16)v[2]; o[3] = (bf16)v[3];
            *reinterpret_cast<bf16x4*>(a_lds + swz128(row, c4 * 2)) = o;
        }
        for (int i = 0; i < 4; ++i) {
            int idx = t + i * 256, row = idx >> 4, c4 = (idx & 15) * 4;
            size_t yoff = ((size_t)b * NPOS + m0 + row) * CMID + k0 + c4;
            float sacc[4] = {0.f, 0.f, 0.f, 0.f};
            for (int p = 0; p < ns; ++p) {
                bf16x4 a = *reinterpret_cast<const bf16x4*>(ys + (size_t)p * SL + yoff);
                for (int r = 0; r < 4; ++r) sacc[r] += (float)a[r];
            }
            bf16x4 o;
            for (int r = 0; r < 4; ++r) o[r] = (bf16)sacc[r];
            *reinterpret_cast<bf16x4*>(b_lds + swz128(row, c4 * 2)) = o;
        }
        __syncthreads();
        for (int ks = 0; ks < 2; ++ks) {
            int kb = ks * 64 + (lane >> 4) * 16;
            bf16x8 af[4], bfr[2];
            for (int i = 0; i < 4; ++i)
                af[i] = *reinterpret_cast<const bf16x8*>(a_lds + swz128(wy * 64 + i * 16 + (lane & 15), kb));
            for (int j = 0; j < 2; ++j)
                bfr[j] = *reinterpret_cast<const bf16x8*>(b_lds + swz128(wx * 32 + j * 16 + (lane & 15), kb));
            for (int i = 0; i < 4; ++i)
                for (int j = 0; j < 2; ++j)
                    acc[i][j] = MFMA16(af[i], bfr[j], acc[i][j]);
        }
    }
    int rg = lane >> 4, cl = lane & 15;
    const float* xb = x + (size_t)b * CIN * NPOS;
    float* ob = out + (size_t)b * CIN * NPOS;
    for (int i = 0; i < 4; ++i) {
        int och0 = o0 + wy * 64 + i * 16 + rg * 4;
        f32x4 gg = *reinterpret_cast<const f32x4*>(gamma + och0);
        f32x4 be = *reinterpret_cast<const f32x4*>(beta + och0);
        f32x4 mu = *reinterpret_cast<const f32x4*>(mean + och0);
        f32x4 va = *reinterpret_cast<const f32x4*>(var + och0);
        f32x4 bb = *reinterpret_cast<const f32x4*>(bw + och0);
        float invv[4], addv[4];
        for (int r = 0; r < 4; ++r) {
            invv[r] = gg[r] / sqrtf(va[r] + EPS);
            addv[r] = be[r] - mu[r] * invv[r];
        }
        for (int j = 0; j < 2; ++j) {
            int m = m0 + wx * 32 + j * 16 + cl;
            for (int r = 0; r < 4; ++r) {
                float z = (acc[i][j][r] + bb[r]) * invv[r] + addv[r];
                ob[(size_t)(och0 + r) * NPOS + m] = z + xb[(size_t)(och0 + r) * NPOS + m];
            }
        }
    }
}

// ---------------------------------------------------------------------------
extern "C" void kernel_launch(void* const* d_in, const int* in_sizes, int n_in,
                              void* d_out, int out_size, void* d_ws, size_t ws_size,
                              hipStream_t stream) {
    const float* x     = (const float*)d_in[0];
    const float* Wq    = (const float*)d_in[1];
    const float* bq    = (const float*)d_in[2];
    const float* Wk    = (const float*)d_in[3];
    const float* bk    = (const float*)d_in[4];
    const float* Wv    = (const float*)d_in[5];
    const float* bv    = (const float*)d_in[6];
    const float* Ww    = (const float*)d_in[7];
    const float* bw    = (const float*)d_in[8];
    const float* gamma = (const float*)d_in[9];
    const float* beta  = (const float*)d_in[10];
    const float* mean  = (const float*)d_in[11];
    const float* var   = (const float*)d_in[12];
    float* out = (float*)d_out;

    const size_t slice = (size_t)BATCH * NPOS * CMID * 2;   // 4 MB

    char* p = (char*)d_ws;
    bf16* ys = (bf16*)p;        p += (size_t)NQATT * slice; // 16 MB (4 slices)
    bf16* qT = (bf16*)p;        p += slice;                 // 4 MB
    bf16* kT = (bf16*)p;        p += slice;                 // 4 MB
    bf16* vC = (bf16*)p;        p += slice;                 // 4 MB
    float* zpart = (float*)p;   p += (size_t)8 * BATCH * NPOS * 4;  // 512 KB
    float* invZ = (float*)p;                                        // 64 KB
    bf16* xT = (bf16*)d_ws;     // overlays ys[0..3]; dead before k_attn writes

    kt_transpose<<<dim3(NPOS / 64, CIN / 64, BATCH), 256, 0, stream>>>(x, xT);
    k_qkv<<<dim3(NPOS / 128, 3, BATCH), 256, 0, stream>>>(Wq, Wk, Wv, bq, bk, bv, xT, qT, kT, vC);
    k_zrow<<<dim3(1024), 256, 0, stream>>>(qT, kT, zpart);
    k_rcp<<<dim3(BATCH * NPOS / 1024), 256, 0, stream>>>(zpart, invZ);
    k_vscale<<<dim3(BATCH * CMID * NPOS / 8 / 256), 256, 0, stream>>>(vC, invZ);
    k_attn<<<dim3(512), 256, 0, stream>>>(qT, kT, vC, ys);
    k_out<<<dim3(NPOS / 64, 2, BATCH), 256, 0, stream>>>(Ww, bw, gamma, beta, mean, var, ys, NQATT, x, out);
}

// Round 14
// 100.389 us; speedup vs baseline: 2.3516x; 1.0505x over previous
//
#include <hip/hip_runtime.h>
#include <hip/hip_bf16.h>

#define BATCH 4
#define CIN   256
#define CMID  128
#define NPOS  4096
#define EPS   1e-5f
#define NQATT 4

typedef __bf16 bf16;
typedef __attribute__((ext_vector_type(8))) __bf16 bf16x8;
typedef __attribute__((ext_vector_type(4))) __bf16 bf16x4;
typedef __attribute__((ext_vector_type(4))) float  f32x4;

#define MFMA16(a, b, c) __builtin_amdgcn_mfma_f32_16x16x32_bf16((a), (b), (c), 0, 0, 0)

// async global->LDS DMA, 16B per lane, dest = wave-uniform base + lane*16
#define GLDS(gsrc, ldst) \
    __builtin_amdgcn_global_load_lds( \
        (const __attribute__((address_space(1))) void*)(gsrc), \
        (__attribute__((address_space(3))) void*)(ldst), 16, 0, 0)

// XOR swizzle, 256B rows (16 chunks/row): chunk ^= row&7.
__device__ __forceinline__ int swz256(int row, int colb) {
    return row * 256 + ((((colb >> 4) ^ (row & 7)) << 4) | (colb & 15));
}
// XOR swizzle, 128B rows (8 chunks/row): chunk ^= row&7.
__device__ __forceinline__ int swz128(int row, int colb) {
    return row * 128 + ((((colb >> 4) ^ (row & 7)) << 4) | (colb & 15));
}

// ---------------------------------------------------------------------------
// K0: convert Wq/Wk/Wv/Ww f32 -> bf16 once (each 32768 elems, same layout).
// Removes per-block redundant f32->bf16 VALU staging from k_qkv / k_out and
// enables pure-DMA operand staging there.
// ---------------------------------------------------------------------------
__global__ __launch_bounds__(256) void k_wcvt(const float* __restrict__ Wq,
                                              const float* __restrict__ Wk,
                                              const float* __restrict__ Wv,
                                              const float* __restrict__ Ww,
                                              bf16* __restrict__ wb) {
    int which = blockIdx.y;
    const float* src = which == 0 ? Wq : which == 1 ? Wk : which == 2 ? Wv : Ww;
    int i = (blockIdx.x * 256 + threadIdx.x) * 8;
    f32x4 v0 = *reinterpret_cast<const f32x4*>(src + i);
    f32x4 v1 = *reinterpret_cast<const f32x4*>(src + i + 4);
    bf16x8 o;
    for (int r = 0; r < 4; ++r) { o[r] = (bf16)v0[r]; o[r + 4] = (bf16)v1[r]; }
    *reinterpret_cast<bf16x8*>(wb + (size_t)which * 32768 + i) = o;
}

// ---------------------------------------------------------------------------
// KT: x [B][CIN][N] f32  ->  xT [B][N][CIN] bf16   (LDS 64x64 tile transpose)
// ---------------------------------------------------------------------------
__global__ __launch_bounds__(256) void kt_transpose(const float* __restrict__ x,
                                                    bf16* __restrict__ xT) {
    __shared__ float tile[64][65];
    int n0 = blockIdx.x * 64, c0 = blockIdx.y * 64, b = blockIdx.z;
    const float* xp = x + (size_t)b * CIN * NPOS;
    int t = threadIdx.x;
    int lr = t >> 4;
    int lc4 = (t & 15) * 4;
    for (int p = 0; p < 4; ++p) {
        int c = lr + p * 16;
        f32x4 v = *reinterpret_cast<const f32x4*>(xp + (size_t)(c0 + c) * NPOS + n0 + lc4);
        tile[c][lc4 + 0] = v[0]; tile[c][lc4 + 1] = v[1];
        tile[c][lc4 + 2] = v[2]; tile[c][lc4 + 3] = v[3];
    }
    __syncthreads();
    bf16* xtp = xT + (size_t)b * NPOS * CIN;
    int cc = (t & 15) * 4;
    for (int p = 0; p < 4; ++p) {
        int n = (t >> 4) + p * 16;
        bf16x4 o;
        o[0] = (bf16)tile[cc + 0][n]; o[1] = (bf16)tile[cc + 1][n];
        o[2] = (bf16)tile[cc + 2][n]; o[3] = (bf16)tile[cc + 3][n];
        *reinterpret_cast<bf16x4*>(xtp + (size_t)(n0 + n) * CIN + c0 + cc) = o;
    }
}

// ---------------------------------------------------------------------------
// K1: q/k/v = W @ x + b.  grid (32 ntile, 3 which, B).
// Both operands bf16, staged via pure DMA into double-buffered LDS (64 KB).
// ---------------------------------------------------------------------------
__global__ __launch_bounds__(256) void k_qkv(
    const bf16* __restrict__ wb,
    const float* __restrict__ bq, const float* __restrict__ bk, const float* __restrict__ bv,
    const bf16* __restrict__ xT, bf16* __restrict__ qT, bf16* __restrict__ kT,
    bf16* __restrict__ vC) {
    __shared__ __align__(16) char a_lds[2][128 * 128];  // [128 o][64 c] swz128
    __shared__ __align__(16) char b_lds[2][128 * 128];  // [128 n][64 c] swz128
    int n0 = blockIdx.x * 128, which = blockIdx.y, b = blockIdx.z;
    const bf16* W = wb + (size_t)which * 32768;          // [128 o][256 c] bf16
    const float* bias = which == 0 ? bq : (which == 1 ? bk : bv);
    int t = threadIdx.x, lane = t & 63, w = t >> 6, wy = w >> 1, wx = w & 1;
    const bf16* xb = xT + (size_t)b * NPOS * CIN;

    auto stage = [&](int buf, int k0) {
        #pragma unroll
        for (int i = 0; i < 4; ++i) {
            int lc = (w * 4 + i) * 64 + lane;            // chunk 0..1023
            int row = lc >> 3, p = lc & 7;               // 8 chunks per 128B row
            GLDS(W + (size_t)row * CIN + k0 + ((p ^ (row & 7)) << 3),
                 a_lds[buf] + (w * 4 + i) * 1024);
            GLDS(xb + (size_t)(n0 + row) * CIN + k0 + ((p ^ (row & 7)) << 3),
                 b_lds[buf] + (w * 4 + i) * 1024);
        }
    };

    f32x4 acc[4][4] = {};
    stage(0, 0);
    asm volatile("s_waitcnt vmcnt(0)" ::: "memory");
    __syncthreads();
    int cur = 0;
    for (int s = 0; s < 4; ++s) {
        if (s < 3) stage(cur ^ 1, (s + 1) * 64);
        for (int ks = 0; ks < 2; ++ks) {
            int kb = ks * 64 + (lane >> 4) * 16;
            bf16x8 af[4], bfr[4];
            for (int i = 0; i < 4; ++i)
                af[i] = *reinterpret_cast<const bf16x8*>(a_lds[cur] + swz128(wy * 64 + i * 16 + (lane & 15), kb));
            for (int j = 0; j < 4; ++j)
                bfr[j] = *reinterpret_cast<const bf16x8*>(b_lds[cur] + swz128(wx * 64 + j * 16 + (lane & 15), kb));
            __builtin_amdgcn_s_setprio(1);
            for (int i = 0; i < 4; ++i)
                for (int j = 0; j < 4; ++j)
                    acc[i][j] = MFMA16(af[i], bfr[j], acc[i][j]);
            __builtin_amdgcn_s_setprio(0);
        }
        __syncthreads();     // reads of cur done; staged buf (vm) drained
        cur ^= 1;
    }
    int rg = lane >> 4, cl = lane & 15;
    for (int i = 0; i < 4; ++i) {
        int ch0 = wy * 64 + i * 16 + rg * 4;
        f32x4 bv4 = *reinterpret_cast<const f32x4*>(bias + ch0);
        for (int j = 0; j < 4; ++j) {
            int n = n0 + wx * 64 + j * 16 + cl;
            f32x4 d = acc[i][j];
            for (int r = 0; r < 4; ++r) d[r] += bv4[r];
            if (which == 2) {
                for (int r = 0; r < 4; ++r)
                    vC[((size_t)b * CMID + ch0 + r) * NPOS + n] = (bf16)d[r];
            } else {
                bf16x4 o; o[0] = (bf16)d[0]; o[1] = (bf16)d[1]; o[2] = (bf16)d[2]; o[3] = (bf16)d[3];
                bf16* dst = (which == 0 ? qT : kT);
                *reinterpret_cast<bf16x4*>(dst + ((size_t)b * NPOS + n) * CMID + ch0) = o;
            }
        }
    }
}

// ---------------------------------------------------------------------------
// K2: zpart[mq][b][n] = sum_{m in eighth mq} exp(S[n,m]).
// Flat grid 1024, XCD-decoded (mq = xcd).  DMA dbuf, 4 blocks/CU.  (r13 body.)
// ---------------------------------------------------------------------------
__global__ __launch_bounds__(256, 4) void k_zrow(const bf16* __restrict__ qT,
                                                 const bf16* __restrict__ kT,
                                                 float* __restrict__ zpart) {
    __shared__ __align__(16) char q_lds[2][64 * 256];  // [64 m][128 c] swz256
    int l = blockIdx.x;
    int xcd = l & 7, slot = l >> 3;
    int mq = xcd, b = slot & 3;
    int n0 = (slot >> 2) * 128;
    int t = threadIdx.x, lane = t & 63, w = t >> 6;
    int cl = lane & 15, g = lane >> 4;
    const bf16* qb = qT + (size_t)b * NPOS * CMID;
    const bf16* kb = kT + (size_t)b * NPOS * CMID;

    auto stage_q = [&](int buf, int m0) {
        #pragma unroll
        for (int i = 0; i < 4; ++i) {
            int lc = (w * 4 + i) * 64 + lane;
            int r = lc >> 4, p = lc & 15;
            GLDS(qb + (size_t)(m0 + r) * CMID + ((p ^ (r & 7)) << 3),
                 q_lds[buf] + (w * 4 + i) * 1024);
        }
    };

    bf16x8 kreg[2][4];
    for (int jn = 0; jn < 2; ++jn)
        for (int ks = 0; ks < 4; ++ks)
            kreg[jn][ks] = *reinterpret_cast<const bf16x8*>(
                kb + (size_t)(n0 + w * 32 + jn * 16 + cl) * CMID + ks * 32 + g * 8);

    int mbeg = mq * (NPOS / 8);
    stage_q(0, mbeg);
    asm volatile("s_waitcnt vmcnt(0)" ::: "memory");
    __syncthreads();
    int cur = 0;
    float zacc[2] = {0.f, 0.f};
    for (int m0 = mbeg; m0 < mbeg + NPOS / 8; m0 += 64) {
        if (m0 + 64 < mbeg + NPOS / 8) stage_q(cur ^ 1, m0 + 64);
        f32x4 acc[4][2] = {};
        __builtin_amdgcn_s_setprio(1);
        for (int ks = 0; ks < 4; ++ks) {
            bf16x8 qf[4];
            for (int im = 0; im < 4; ++im)
                qf[im] = *reinterpret_cast<const bf16x8*>(q_lds[cur] + swz256(im * 16 + cl, ks * 64 + g * 16));
            for (int im = 0; im < 4; ++im)
                for (int jn = 0; jn < 2; ++jn)
                    acc[im][jn] = MFMA16(qf[im], kreg[jn][ks], acc[im][jn]);
        }
        __builtin_amdgcn_s_setprio(0);
        for (int im = 0; im < 4; ++im)
            for (int jn = 0; jn < 2; ++jn)
                for (int r = 0; r < 4; ++r)
                    zacc[jn] += __expf(acc[im][jn][r]);
        __syncthreads();
        cur ^= 1;
    }
    for (int jn = 0; jn < 2; ++jn) {
        zacc[jn] += __shfl_xor(zacc[jn], 16);
        zacc[jn] += __shfl_xor(zacc[jn], 32);
    }
    if (g == 0) {
        float* zp = zpart + ((size_t)mq * BATCH + b) * NPOS;
        zp[n0 + w * 32 + cl]      = zacc[0];
        zp[n0 + w * 32 + 16 + cl] = zacc[1];
    }
}

// ---------------------------------------------------------------------------
// K3: invZ = 1 / sum_{s<8} zpart[s].
// ---------------------------------------------------------------------------
__global__ __launch_bounds__(256) void k_rcp(const float* __restrict__ zpart,
                                             float* __restrict__ invZ) {
    int i = (blockIdx.x * 256 + threadIdx.x) * 4;
    f32x4 s = {0.f, 0.f, 0.f, 0.f};
    for (int p = 0; p < 8; ++p) {
        f32x4 a = *reinterpret_cast<const f32x4*>(zpart + (size_t)p * BATCH * NPOS + i);
        for (int r = 0; r < 4; ++r) s[r] += a[r];
    }
    f32x4 o;
    for (int r = 0; r < 4; ++r) o[r] = 1.f / s[r];
    *reinterpret_cast<f32x4*>(invZ + i) = o;
}

// ---------------------------------------------------------------------------
// K3b: vC[c,n] *= invZ[n]  (in-place).
// ---------------------------------------------------------------------------
__global__ __launch_bounds__(256) void k_vscale(bf16* __restrict__ vC,
                                                const float* __restrict__ invZ) {
    int idx = blockIdx.x * 256 + threadIdx.x;
    int b = idx >> 16;
    int n8 = idx & (NPOS / 8 - 1);
    bf16x8 v = *reinterpret_cast<const bf16x8*>(vC + (size_t)idx * 8);
    const float* iz = invZ + (size_t)b * NPOS + n8 * 8;
    f32x4 i0 = *reinterpret_cast<const f32x4*>(iz);
    f32x4 i1 = *reinterpret_cast<const f32x4*>(iz + 4);
    bf16x8 o;
    for (int r = 0; r < 4; ++r) {
        o[r]     = (bf16)((float)v[r]     * i0[r]);
        o[r + 4] = (bf16)((float)v[r + 4] * i1[r]);
    }
    *reinterpret_cast<bf16x8*>(vC + (size_t)idx * 8) = o;
}

// ---------------------------------------------------------------------------
// K4: y[m][c] = sum_n exp(S[n,m]) vs[c,n]  (r13-measured-best body, 42.7us).
// ---------------------------------------------------------------------------
__global__ __launch_bounds__(256, 2) void k_attn(const bf16* __restrict__ qT,
                                                 const bf16* __restrict__ kT,
                                                 const bf16* __restrict__ vS,
                                                 bf16* __restrict__ ys) {
    __shared__ __align__(16) char k_lds[2][64 * 256];   // [64 n][128 c] swz256
    __shared__ __align__(16) char v_lds[2][128 * 128];  // [128 c][64 n] swz128
    __shared__ __align__(16) char p_lds[128 * 128];     // [128 m][64 n] swz128
    int l = blockIdx.x;
    int xcd = l & 7, slot = l >> 3;
    int combo = xcd * 2 + (slot & 1);                // 16 combos (nq,b), 2/XCD
    int m0 = (slot >> 1) * 128;
    int nq = combo >> 2, b = combo & 3;
    int t = threadIdx.x, lane = t & 63, w = t >> 6;
    int cl = lane & 15, g = lane >> 4;
    const bf16* qb = qT + (size_t)b * NPOS * CMID;
    const bf16* kb = kT + (size_t)b * NPOS * CMID;
    const bf16* vb = vS + (size_t)b * CMID * NPOS;

    auto stage_kv = [&](int buf, int n0) {
        #pragma unroll
        for (int i = 0; i < 4; ++i) {
            int lc = (w * 4 + i) * 64 + lane;        // 16B-chunk idx in tile
            int kr = lc >> 4, kp = lc & 15;          // k: 16 chunks/row
            GLDS(kb + (size_t)(n0 + kr) * CMID + ((kp ^ (kr & 7)) << 3),
                 k_lds[buf] + (w * 4 + i) * 1024);
            int vr = lc >> 3, vp = lc & 7;           // v: 8 chunks/row
            GLDS(vb + (size_t)vr * NPOS + n0 + ((vp ^ (vr & 7)) << 3),
                 v_lds[buf] + (w * 4 + i) * 1024);
        }
    };

    // q fragments (B-operand): wave owns m-cols m0 + w*32 + jm*16 + cl
    bf16x8 qreg[2][4];
    for (int jm = 0; jm < 2; ++jm)
        for (int ks = 0; ks < 4; ++ks)
            qreg[jm][ks] = *reinterpret_cast<const bf16x8*>(
                qb + (size_t)(m0 + w * 32 + jm * 16 + cl) * CMID + ks * 32 + g * 8);

    f32x4 acc2[2][8] = {};                           // y[m: wave's 32][c: 128]
    int nbeg = nq * (NPOS / NQATT);
    stage_kv(0, nbeg);
    asm volatile("s_waitcnt vmcnt(0)" ::: "memory");
    __syncthreads();
    int cur = 0;
    for (int s = 0; s < NPOS / NQATT / 64; ++s) {
        int n0 = nbeg + s * 64;
        if (s + 1 < NPOS / NQATT / 64) stage_kv(cur ^ 1, n0 + 64);
        // S^T: acc1[in][jm] = D[n = in*16+g*4+r][m = w*32+jm*16+cl]
        f32x4 acc1[4][2] = {};
        __builtin_amdgcn_s_setprio(1);
        for (int ks = 0; ks < 4; ++ks) {
            bf16x8 kf[4];
            for (int in = 0; in < 4; ++in)
                kf[in] = *reinterpret_cast<const bf16x8*>(k_lds[cur] + swz256(in * 16 + cl, ks * 64 + g * 16));
            for (int in = 0; in < 4; ++in)
                for (int jm = 0; jm < 2; ++jm)
                    acc1[in][jm] = MFMA16(kf[in], qreg[jm][ks], acc1[in][jm]);
        }
        __builtin_amdgcn_s_setprio(0);
        // P^T[m][n] = exp(S), wave-private rows (lane writes 4 consecutive n).
        for (int in = 0; in < 4; ++in)
            for (int jm = 0; jm < 2; ++jm) {
                bf16x4 o;
                for (int r = 0; r < 4; ++r) o[r] = (bf16)__expf(acc1[in][jm][r]);
                *reinterpret_cast<bf16x4*>(p_lds + swz128(w * 32 + jm * 16 + cl, in * 32 + g * 8)) = o;
            }
        // PV m-split: A = own P rows, B = all v c-tiles. No barrier needed.
        __builtin_amdgcn_s_setprio(1);
        for (int s32 = 0; s32 < 2; ++s32) {
            bf16x8 af[2], vf[8];
            for (int jm = 0; jm < 2; ++jm)
                af[jm] = *reinterpret_cast<const bf16x8*>(p_lds + swz128(w * 32 + jm * 16 + cl, s32 * 64 + g * 16));
            for (int j = 0; j < 8; ++j)
                vf[j] = *reinterpret_cast<const bf16x8*>(v_lds[cur] + swz128(j * 16 + cl, s32 * 64 + g * 16));
            for (int jm = 0; jm < 2; ++jm)
                for (int j = 0; j < 8; ++j)
                    acc2[jm][j] = MFMA16(af[jm], vf[j], acc2[jm][j]);
        }
        __builtin_amdgcn_s_setprio(0);
        __syncthreads();   // staged buf ready (vm drained) + reads of cur done
        cur ^= 1;
    }
    bf16* yb = ys + (size_t)nq * BATCH * NPOS * CMID
             + ((size_t)b * NPOS + m0) * CMID;
    for (int jm = 0; jm < 2; ++jm)
        for (int j = 0; j < 8; ++j) {
            int c = j * 16 + cl;
            for (int r = 0; r < 4; ++r) {
                int m = w * 32 + jm * 16 + g * 4 + r;
                yb[(size_t)m * CMID + c] = (bf16)acc2[jm][j][r];
            }
        }
}

// ---------------------------------------------------------------------------
// K5: out = (Ww @ sum_{s<ns} y_s + bw)*inv + add + x.
// grid (128 mtile(32), B).  o-tile = 256 (full) -> ys read ONCE; whole Ww
// (bf16, 64KB) DMA-staged once; single barrier; 32 MFMA/wave; epilogue.
// LDS 72KB -> 2 blocks/CU.
// ---------------------------------------------------------------------------
__global__ __launch_bounds__(256) void k_out(
    const bf16* __restrict__ Wwb, const float* __restrict__ bw,
    const float* __restrict__ gamma, const float* __restrict__ beta,
    const float* __restrict__ mean, const float* __restrict__ var,
    const bf16* __restrict__ ys, int ns,
    const float* __restrict__ x, float* __restrict__ out) {
    __shared__ __align__(16) char a_lds[256 * 256];  // [256 o][128 c] swz256
    __shared__ __align__(16) char b_lds[32 * 256];   // [32 m][128 c] swz256
    int m0 = blockIdx.x * 32, b = blockIdx.y;
    int t = threadIdx.x, lane = t & 63, w = t >> 6;
    int cl = lane & 15, g = lane >> 4;
    const size_t SL = (size_t)BATCH * NPOS * CMID;   // slice stride (elems)

    // stage a: whole Ww [256 o][128 c] bf16, 4096 chunks, pure DMA.
    #pragma unroll
    for (int i = 0; i < 16; ++i) {
        int lc = (w * 16 + i) * 64 + lane;           // chunk 0..4095
        int row = lc >> 4, p = lc & 15;              // 16 chunks per 256B row
        GLDS(Wwb + (size_t)row * CMID + ((p ^ (row & 7)) << 3),
             a_lds + (w * 16 + i) * 1024);
    }
    // stage b: sum of ns y-slices, rows m0..m0+31, all 128 c (VALU path).
    for (int i = 0; i < 2; ++i) {
        int lc = t * 2 + i;                          // chunk 0..511
        int row = lc >> 4, cb = (lc & 15) * 16;      // 16 chunks per 256B row
        size_t yoff = ((size_t)b * NPOS + m0 + row) * CMID + cb / 2;
        float sacc[8] = {};
        for (int p = 0; p < ns; ++p) {
            bf16x8 a = *reinterpret_cast<const bf16x8*>(ys + (size_t)p * SL + yoff);
            for (int r = 0; r < 8; ++r) sacc[r] += (float)a[r];
        }
        bf16x8 o;
        for (int r = 0; r < 8; ++r) o[r] = (bf16)sacc[r];
        *reinterpret_cast<bf16x8*>(b_lds + swz256(row, cb)) = o;
    }
    asm volatile("s_waitcnt vmcnt(0)" ::: "memory");
    __syncthreads();

    // MFMA: wave owns o-range w*64..w*64+63; full K=128.
    f32x4 acc[4][2] = {};
    for (int ks = 0; ks < 4; ++ks) {
        int kb = ks * 64 + g * 16;
        bf16x8 af[4], bfr[2];
        for (int i = 0; i < 4; ++i)
            af[i] = *reinterpret_cast<const bf16x8*>(a_lds + swz256(w * 64 + i * 16 + cl, kb));
        for (int j = 0; j < 2; ++j)
            bfr[j] = *reinterpret_cast<const bf16x8*>(b_lds + swz256(j * 16 + cl, kb));
        __builtin_amdgcn_s_setprio(1);
        for (int i = 0; i < 4; ++i)
            for (int j = 0; j < 2; ++j)
                acc[i][j] = MFMA16(af[i], bfr[j], acc[i][j]);
        __builtin_amdgcn_s_setprio(0);
    }

    const float* xb = x + (size_t)b * CIN * NPOS;
    float* ob = out + (size_t)b * CIN * NPOS;
    for (int i = 0; i < 4; ++i) {
        int och0 = w * 64 + i * 16 + g * 4;
        f32x4 gg = *reinterpret_cast<const f32x4*>(gamma + och0);
        f32x4 be = *reinterpret_cast<const f32x4*>(beta + och0);
        f32x4 mu = *reinterpret_cast<const f32x4*>(mean + och0);
        f32x4 va = *reinterpret_cast<const f32x4*>(var + och0);
        f32x4 bb = *reinterpret_cast<const f32x4*>(bw + och0);
        float invv[4], addv[4];
        for (int r = 0; r < 4; ++r) {
            invv[r] = gg[r] / sqrtf(va[r] + EPS);
            addv[r] = be[r] - mu[r] * invv[r];
        }
        for (int j = 0; j < 2; ++j) {
            int m = m0 + j * 16 + cl;
            for (int r = 0; r < 4; ++r) {
                float z = (acc[i][j][r] + bb[r]) * invv[r] + addv[r];
                ob[(size_t)(och0 + r) * NPOS + m] = z + xb[(size_t)(och0 + r) * NPOS + m];
            }
        }
    }
}

// ---------------------------------------------------------------------------
extern "C" void kernel_launch(void* const* d_in, const int* in_sizes, int n_in,
                              void* d_out, int out_size, void* d_ws, size_t ws_size,
                              hipStream_t stream) {
    const float* x     = (const float*)d_in[0];
    const float* Wq    = (const float*)d_in[1];
    const float* bq    = (const float*)d_in[2];
    const float* Wk    = (const float*)d_in[3];
    const float* bk    = (const float*)d_in[4];
    const float* Wv    = (const float*)d_in[5];
    const float* bv    = (const float*)d_in[6];
    const float* Ww    = (const float*)d_in[7];
    const float* bw    = (const float*)d_in[8];
    const float* gamma = (const float*)d_in[9];
    const float* beta  = (const float*)d_in[10];
    const float* mean  = (const float*)d_in[11];
    const float* var   = (const float*)d_in[12];
    float* out = (float*)d_out;

    const size_t slice = (size_t)BATCH * NPOS * CMID * 2;   // 4 MB

    char* p = (char*)d_ws;
    bf16* ys = (bf16*)p;        p += (size_t)NQATT * slice; // 16 MB (4 slices)
    bf16* qT = (bf16*)p;        p += slice;                 // 4 MB
    bf16* kT = (bf16*)p;        p += slice;                 // 4 MB
    bf16* vC = (bf16*)p;        p += slice;                 // 4 MB
    float* zpart = (float*)p;   p += (size_t)8 * BATCH * NPOS * 4;  // 512 KB
    float* invZ = (float*)p;    p += (size_t)BATCH * NPOS * 4;      // 64 KB
    bf16* wbuf = (bf16*)p;                                          // 256 KB
    bf16* xT = (bf16*)d_ws;     // overlays ys[0..3]; dead before k_attn writes

    k_wcvt<<<dim3(16, 4), 256, 0, stream>>>(Wq, Wk, Wv, Ww, wbuf);
    kt_transpose<<<dim3(NPOS / 64, CIN / 64, BATCH), 256, 0, stream>>>(x, xT);
    k_qkv<<<dim3(NPOS / 128, 3, BATCH), 256, 0, stream>>>(wbuf, bq, bk, bv, xT, qT, kT, vC);
    k_zrow<<<dim3(1024), 256, 0, stream>>>(qT, kT, zpart);
    k_rcp<<<dim3(BATCH * NPOS / 1024), 256, 0, stream>>>(zpart, invZ);
    k_vscale<<<dim3(BATCH * CMID * NPOS / 8 / 256), 256, 0, stream>>>(vC, invZ);
    k_attn<<<dim3(512), 256, 0, stream>>>(qT, kT, vC, ys);
    k_out<<<dim3(NPOS / 32, BATCH), 256, 0, stream>>>(wbuf + 3 * 32768, bw, gamma, beta, mean, var, ys, NQATT, x, out);
}